// Round 8
// baseline (735.682 us; speedup 1.0000x reference)
//
#include <hip/hip_runtime.h>
#include <stdint.h>

#define U_CNT 300000
#define I_CNT 200000
#define N_CNT 500000
#define DIM 64
#define SCAN_CHUNK 1024
#define NB1 ((N_CNT + SCAN_CHUNK - 1) / SCAN_CHUNK)   // 489

typedef unsigned short bf16_t;
typedef float    f32x4 __attribute__((ext_vector_type(4)));
typedef uint32_t u32x4 __attribute__((ext_vector_type(4)));

__device__ __forceinline__ float lof(uint32_t u) { return __uint_as_float(u << 16); }
__device__ __forceinline__ float hif(uint32_t u) { return __uint_as_float(u & 0xFFFF0000u); }
__device__ __forceinline__ uint32_t rnd_bf(float f) {
    uint32_t u = __float_as_uint(f);
    return u + (0x7FFFu + ((u >> 16) & 1u));      // rne, still in high bits
}
__device__ __forceinline__ uint32_t packbf(float lo, float hi) {
    return (rnd_bf(lo) >> 16) | (rnd_bf(hi) & 0xFFFF0000u);
}
__device__ __forceinline__ bf16_t f2b(float f) { return (bf16_t)(rnd_bf(f) >> 16); }

// ---------------- degree ----------------

__global__ void deg_cnt_kernel(const int* __restrict__ col, int* __restrict__ cnt, int E) {
    int e = blockIdx.x * blockDim.x + threadIdx.x;
    if (e < E) atomicAdd(&cnt[col[e]], 1);
}

// ---------------- scan1 + normalization arrays ----------------
// dis = 1/sqrt(deg), dis2 = 1/deg, rdis = sqrt(deg)  (0 when deg==0)

__global__ void scan1_dis_kernel(const int* __restrict__ cnt, int* __restrict__ bsum,
                                 float* __restrict__ dis, float* __restrict__ dis2,
                                 float* __restrict__ rdis, int n) {
    __shared__ int lds[256];
    int t = threadIdx.x;
    int i = blockIdx.x * SCAN_CHUNK + t * 4;
    int4 v = make_int4(0, 0, 0, 0);
    if (i + 3 < n) v = *(const int4*)(cnt + i);
    else {
        if (i     < n) v.x = cnt[i];
        if (i + 1 < n) v.y = cnt[i + 1];
        if (i + 2 < n) v.z = cnt[i + 2];
        if (i + 3 < n) v.w = cnt[i + 3];
    }
    if (i + 3 < n) {
        int dd[4] = {v.x, v.y, v.z, v.w};
        f32x4 fd, f2, fr;
        #pragma unroll
        for (int k = 0; k < 4; k++) {
            float d = (float)dd[k];
            float s = dd[k] > 0 ? rsqrtf(d) : 0.0f;
            fd[k] = s; f2[k] = s * s; fr[k] = d * s;
        }
        *(f32x4*)(dis + i) = fd;
        *(f32x4*)(dis2 + i) = f2;
        *(f32x4*)(rdis + i) = fr;
    } else {
        for (int k = 0; k < 4 && i + k < n; k++) {
            int d = (&v.x)[k];
            float s = d > 0 ? rsqrtf((float)d) : 0.0f;
            dis[i + k] = s; dis2[i + k] = s * s; rdis[i + k] = (float)d * s;
        }
    }
    lds[t] = v.x + v.y + v.z + v.w;
    __syncthreads();
    for (int o = 128; o > 0; o >>= 1) {
        if (t < o) lds[t] += lds[t + o];
        __syncthreads();
    }
    if (t == 0) bsum[blockIdx.x] = lds[0];
}

__global__ void scan2_kernel(int* __restrict__ bsum, int nb) {
    __shared__ int lds[512];
    int t = threadIdx.x;
    int v = (t < nb) ? bsum[t] : 0;
    lds[t] = v;
    __syncthreads();
    for (int o = 1; o < 512; o <<= 1) {
        int a = lds[t] + ((t >= o) ? lds[t - o] : 0);
        __syncthreads();
        lds[t] = a;
        __syncthreads();
    }
    if (t < nb) bsum[t] = lds[t] - v;
}

__global__ void scan3_kernel(const int* __restrict__ cnt, const int* __restrict__ bsum,
                             int* __restrict__ off, int* __restrict__ cur, int n, int E) {
    __shared__ int lds[256];
    int t = threadIdx.x;
    int i = blockIdx.x * SCAN_CHUNK + t * 4;
    int4 v = make_int4(0, 0, 0, 0);
    if (i + 3 < n) v = *(const int4*)(cnt + i);
    else {
        if (i     < n) v.x = cnt[i];
        if (i + 1 < n) v.y = cnt[i + 1];
        if (i + 2 < n) v.z = cnt[i + 2];
        if (i + 3 < n) v.w = cnt[i + 3];
    }
    int s = v.x + v.y + v.z + v.w;
    lds[t] = s;
    __syncthreads();
    for (int o = 1; o < 256; o <<= 1) {
        int a = lds[t] + ((t >= o) ? lds[t - o] : 0);
        __syncthreads();
        lds[t] = a;
        __syncthreads();
    }
    int ex = lds[t] - s + bsum[blockIdx.x];
    int o0 = ex, o1 = ex + v.x, o2 = o1 + v.y, o3 = o2 + v.z;
    if (i     < n) { off[i]     = o0; cur[i]     = o0; }
    if (i + 1 < n) { off[i + 1] = o1; cur[i + 1] = o1; }
    if (i + 2 < n) { off[i + 2] = o2; cur[i + 2] = o2; }
    if (i + 3 < n) { off[i + 3] = o3; cur[i + 3] = o3; }
    if (i == n - 4) off[n] = E;   // N_CNT % 4 == 0
}

// ---------------- fill (int CSR) fused with w0 = dis * x0 conversion ----------------

__global__ void fill_w0_kernel(const int* __restrict__ row, const int* __restrict__ col,
                               int* __restrict__ cur, int* __restrict__ csr, int E, int gE,
                               const float* __restrict__ embU, const float* __restrict__ embIadj,
                               const float* __restrict__ dis, ushort4* __restrict__ w0) {
    int b = blockIdx.x;
    if (b < gE) {
        int e = b * blockDim.x + threadIdx.x;
        if (e < E) {
            int r = row[e], c = col[e];
            int p = atomicAdd(&cur[c], 1);
            csr[p] = r;
        }
    } else {
        int q = (b - gE) * blockDim.x + threadIdx.x;   // float4 index, exactly N_CNT*16 total
        int node = q >> 4;
        const float* src = (node < U_CNT ? embU : embIadj);
        f32x4 v = __builtin_nontemporal_load((const f32x4*)src + q);
        float dn = dis[node];
        ushort4 w;
        w.x = f2b(v[0] * dn); w.y = f2b(v[1] * dn);
        w.z = f2b(v[2] * dn); w.w = f2b(v[3] * dn);
        w0[q] = w;
    }
}

// ---------------- gather propagation (layers 1..3) ----------------
// w_out[c] = dis2[c] * sum_{r in N(c)} w_in[r]   (8 lanes/node, uint4 = 8 bf16)
// Optional: s_out = w1 + w2 + w_out (bf16, nt)  [layer 3]
// Optional: verbatim emb copy for nodes in [cpyLo, cpyHi)  [layers 1, 2]
__global__ __launch_bounds__(256) void gatherw_kernel(
        const int* __restrict__ off, const int* __restrict__ csr,
        const uint32_t* __restrict__ w_in, uint4* __restrict__ w_out,
        const float* __restrict__ dis2, int nE,
        u32x4* __restrict__ s_out, const u32x4* __restrict__ w1, const u32x4* __restrict__ w2,
        const float* __restrict__ cpySrc, float* __restrict__ cpyDst, int cpyLo, int cpyHi) {
    int lane = threadIdx.x & 63;
    int sub  = lane & 7;
    int n = blockIdx.x * 32 + (threadIdx.x >> 6) * 8 + (lane >> 3);  // N_CNT % 32 == 0
    int s = off[n], e = off[n + 1];
    const uint4* xv = (const uint4*)w_in;
    size_t nodeOff = ((size_t)n << 3) + sub;

    // early independent streaming loads (overlap the gather loop)
    u32x4 u1 = {0, 0, 0, 0}, u2 = {0, 0, 0, 0};
    if (s_out) {
        u1 = __builtin_nontemporal_load(w1 + nodeOff);
        u2 = __builtin_nontemporal_load(w2 + nodeOff);
    }
    f32x4 cb0, cb1;
    bool doCpy = (cpyDst != nullptr) && (n >= cpyLo) && (n < cpyHi);
    size_t fbase = ((size_t)n << 6) + (size_t)sub * 8;
    if (doCpy) {
        cb0 = __builtin_nontemporal_load((const f32x4*)(cpySrc + fbase));
        cb1 = __builtin_nontemporal_load((const f32x4*)(cpySrc + fbase + 4));
    }

    float a0 = 0, a1 = 0, a2 = 0, a3 = 0, a4 = 0, a5 = 0, a6 = 0, a7 = 0;

    int i0 = s;
    int ca = csr[(i0     < nE) ? i0     : (nE - 1)];
    int cb = csr[(i0 + 1 < nE) ? i0 + 1 : (nE - 1)];
    float na = (i0     < e) ? 1.0f : 0.0f;
    float nb = (i0 + 1 < e) ? 1.0f : 0.0f;
    int   ra = (i0     < e) ? ca : 0;
    int   rb = (i0 + 1 < e) ? cb : 0;
    uint4 va = xv[((size_t)ra << 3) + sub];
    uint4 vb = xv[((size_t)rb << 3) + sub];
    int i1 = i0 + 2;
    int qa = csr[(i1     < nE) ? i1     : (nE - 1)];
    int qb = csr[(i1 + 1 < nE) ? i1 + 1 : (nE - 1)];

    while (i0 < e) {
        float ma = (i1     < e) ? 1.0f : 0.0f;
        float mb = (i1 + 1 < e) ? 1.0f : 0.0f;
        int   sa = (i1     < e) ? qa : 0;
        int   sb = (i1 + 1 < e) ? qb : 0;
        uint4 wa = xv[((size_t)sa << 3) + sub];
        uint4 wb = xv[((size_t)sb << 3) + sub];
        int i2 = i1 + 2;
        qa = csr[(i2     < nE) ? i2     : (nE - 1)];
        qb = csr[(i2 + 1 < nE) ? i2 + 1 : (nE - 1)];
        a0 = fmaf(na, lof(va.x), a0); a1 = fmaf(na, hif(va.x), a1);
        a2 = fmaf(na, lof(va.y), a2); a3 = fmaf(na, hif(va.y), a3);
        a4 = fmaf(na, lof(va.z), a4); a5 = fmaf(na, hif(va.z), a5);
        a6 = fmaf(na, lof(va.w), a6); a7 = fmaf(na, hif(va.w), a7);
        a0 = fmaf(nb, lof(vb.x), a0); a1 = fmaf(nb, hif(vb.x), a1);
        a2 = fmaf(nb, lof(vb.y), a2); a3 = fmaf(nb, hif(vb.y), a3);
        a4 = fmaf(nb, lof(vb.z), a4); a5 = fmaf(nb, hif(vb.z), a5);
        a6 = fmaf(nb, lof(vb.w), a6); a7 = fmaf(nb, hif(vb.w), a7);
        va = wa; vb = wb; na = ma; nb = mb;
        i0 = i1; i1 = i2;
    }

    float d2 = dis2[n];
    a0 *= d2; a1 *= d2; a2 *= d2; a3 *= d2;
    a4 *= d2; a5 *= d2; a6 *= d2; a7 *= d2;

    uint4 w;
    w.x = packbf(a0, a1); w.y = packbf(a2, a3);
    w.z = packbf(a4, a5); w.w = packbf(a6, a7);
    w_out[nodeOff] = w;   // cached: gather source of next layer

    if (s_out) {
        u32x4 sv;
        sv[0] = packbf(lof(u1[0]) + lof(u2[0]) + a0, hif(u1[0]) + hif(u2[0]) + a1);
        sv[1] = packbf(lof(u1[1]) + lof(u2[1]) + a2, hif(u1[1]) + hif(u2[1]) + a3);
        sv[2] = packbf(lof(u1[2]) + lof(u2[2]) + a4, hif(u1[2]) + hif(u2[2]) + a5);
        sv[3] = packbf(lof(u1[3]) + lof(u2[3]) + a6, hif(u1[3]) + hif(u2[3]) + a7);
        __builtin_nontemporal_store(sv, s_out + nodeOff);
    }
    if (doCpy) {
        __builtin_nontemporal_store(cb0, (f32x4*)(cpyDst + fbase));
        __builtin_nontemporal_store(cb1, (f32x4*)(cpyDst + fbase + 4));
    }
}

// ---------------- final: gather layer 4 + finalize ----------------
// t4 = sum w3[r]; y4 = dis[c]*t4; fin = (emb + rdis*s3 + y4)/25

__global__ __launch_bounds__(256) void final_kernel(
        const int* __restrict__ off, const int* __restrict__ csr,
        const uint32_t* __restrict__ w3, const u32x4* __restrict__ s3,
        const float* __restrict__ embU, const float* __restrict__ embIadj,
        const float* __restrict__ dis, const float* __restrict__ rdis,
        float* __restrict__ finU, float* __restrict__ finIadj, int nE) {
    int lane = threadIdx.x & 63;
    int sub  = lane & 7;
    int n = blockIdx.x * 32 + (threadIdx.x >> 6) * 8 + (lane >> 3);
    int s = off[n], e = off[n + 1];
    const uint4* xv = (const uint4*)w3;
    size_t nodeOff = ((size_t)n << 3) + sub;
    size_t fbase   = ((size_t)n << 6) + (size_t)sub * 8;

    const float* embP = (n < U_CNT ? embU : embIadj) + fbase;
    float*       finP = (n < U_CNT ? finU : finIadj) + fbase;
    f32x4 b0 = __builtin_nontemporal_load((const f32x4*)embP);
    f32x4 b1 = __builtin_nontemporal_load((const f32x4*)(embP + 4));
    u32x4 u3 = __builtin_nontemporal_load(s3 + nodeOff);

    float a0 = 0, a1 = 0, a2 = 0, a3 = 0, a4 = 0, a5 = 0, a6 = 0, a7 = 0;

    int i0 = s;
    int ca = csr[(i0     < nE) ? i0     : (nE - 1)];
    int cb = csr[(i0 + 1 < nE) ? i0 + 1 : (nE - 1)];
    float na = (i0     < e) ? 1.0f : 0.0f;
    float nb = (i0 + 1 < e) ? 1.0f : 0.0f;
    int   ra = (i0     < e) ? ca : 0;
    int   rb = (i0 + 1 < e) ? cb : 0;
    uint4 va = xv[((size_t)ra << 3) + sub];
    uint4 vb = xv[((size_t)rb << 3) + sub];
    int i1 = i0 + 2;
    int qa = csr[(i1     < nE) ? i1     : (nE - 1)];
    int qb = csr[(i1 + 1 < nE) ? i1 + 1 : (nE - 1)];

    while (i0 < e) {
        float ma = (i1     < e) ? 1.0f : 0.0f;
        float mb = (i1 + 1 < e) ? 1.0f : 0.0f;
        int   sa = (i1     < e) ? qa : 0;
        int   sb = (i1 + 1 < e) ? qb : 0;
        uint4 wa = xv[((size_t)sa << 3) + sub];
        uint4 wb = xv[((size_t)sb << 3) + sub];
        int i2 = i1 + 2;
        qa = csr[(i2     < nE) ? i2     : (nE - 1)];
        qb = csr[(i2 + 1 < nE) ? i2 + 1 : (nE - 1)];
        a0 = fmaf(na, lof(va.x), a0); a1 = fmaf(na, hif(va.x), a1);
        a2 = fmaf(na, lof(va.y), a2); a3 = fmaf(na, hif(va.y), a3);
        a4 = fmaf(na, lof(va.z), a4); a5 = fmaf(na, hif(va.z), a5);
        a6 = fmaf(na, lof(va.w), a6); a7 = fmaf(na, hif(va.w), a7);
        a0 = fmaf(nb, lof(vb.x), a0); a1 = fmaf(nb, hif(vb.x), a1);
        a2 = fmaf(nb, lof(vb.y), a2); a3 = fmaf(nb, hif(vb.y), a3);
        a4 = fmaf(nb, lof(vb.z), a4); a5 = fmaf(nb, hif(vb.z), a5);
        a6 = fmaf(nb, lof(vb.w), a6); a7 = fmaf(nb, hif(vb.w), a7);
        va = wa; vb = wb; na = ma; nb = mb;
        i0 = i1; i1 = i2;
    }

    float dn = dis[n];
    float rd = rdis[n];
    const float k = 1.0f / 25.0f;
    f32x4 r0, r1;
    r0[0] = (b0[0] + rd * lof(u3[0]) + dn * a0) * k;
    r0[1] = (b0[1] + rd * hif(u3[0]) + dn * a1) * k;
    r0[2] = (b0[2] + rd * lof(u3[1]) + dn * a2) * k;
    r0[3] = (b0[3] + rd * hif(u3[1]) + dn * a3) * k;
    r1[0] = (b1[0] + rd * lof(u3[2]) + dn * a4) * k;
    r1[1] = (b1[1] + rd * hif(u3[2]) + dn * a5) * k;
    r1[2] = (b1[2] + rd * lof(u3[3]) + dn * a6) * k;
    r1[3] = (b1[3] + rd * hif(u3[3]) + dn * a7) * k;
    __builtin_nontemporal_store(r0, (f32x4*)finP);
    __builtin_nontemporal_store(r1, (f32x4*)(finP + 4));
}

// ---------------- host ----------------

extern "C" void kernel_launch(void* const* d_in, const int* in_sizes, int n_in,
                              void* d_out, int out_size, void* d_ws, size_t ws_size,
                              hipStream_t stream) {
    const int*   edge = (const int*)d_in[0];
    const float* embU = (const float*)d_in[1];
    const float* embI = (const float*)d_in[2];
    const int E = in_sizes[0] / 2;
    const int* row = edge;
    const int* col = edge + E;

    float* out  = (float*)d_out;
    float* finU = out;
    float* cu   = out + (size_t)U_CNT * DIM;
    float* finI = out + (size_t)2 * U_CNT * DIM;
    float* ci   = finI + (size_t)I_CNT * DIM;

    // workspace carve-up
    const size_t XB = (size_t)N_CNT * DIM * sizeof(bf16_t);   // 64 MB
    char* ws = (char*)d_ws;
    size_t p = 0;
    bf16_t* w0 = (bf16_t*)(ws + p); p += XB;
    bf16_t* w1 = (bf16_t*)(ws + p); p += XB;
    bf16_t* w2 = (bf16_t*)(ws + p); p += XB;
    bf16_t* w3 = (bf16_t*)(ws + p); p += XB;
    bf16_t* s3 = (bf16_t*)(ws + p); p += XB;
    int*   cnt  = (int*)(ws + p);   p += ((size_t)N_CNT + 4) * sizeof(int);
    int*   off  = (int*)(ws + p);   p += ((size_t)N_CNT + 4) * sizeof(int);
    int*   cur  = (int*)(ws + p);   p += ((size_t)N_CNT + 4) * sizeof(int);
    float* dis  = (float*)(ws + p); p += ((size_t)N_CNT + 4) * sizeof(float);
    float* dis2 = (float*)(ws + p); p += ((size_t)N_CNT + 4) * sizeof(float);
    float* rdis = (float*)(ws + p); p += ((size_t)N_CNT + 4) * sizeof(float);
    int*   bsum = (int*)(ws + p);   p += 1024 * sizeof(int);
    int*   csr  = (int*)(ws + p);   p += (size_t)E * sizeof(int);               // 10 MB

    // adjusted item pointers (index by global node id)
    const float* embIadj = embI - (size_t)U_CNT * DIM;
    float* finIadj = finI - (size_t)U_CNT * DIM;
    float* ciadj   = ci   - (size_t)U_CNT * DIM;

    const int B = 256;
    const int gE  = (E + B - 1) / B;
    const int gW  = N_CNT * 16 / B;     // 31250 float4-blocks, exact
    const int gGather = N_CNT / 32;     // 15625, exact

    // 1. degree
    hipMemsetAsync(cnt, 0, (size_t)N_CNT * sizeof(int), stream);
    deg_cnt_kernel<<<gE, B, 0, stream>>>(col, cnt, E);

    // 2. scan + normalization arrays
    scan1_dis_kernel<<<NB1, 256, 0, stream>>>(cnt, bsum, dis, dis2, rdis, N_CNT);
    scan2_kernel<<<1, 512, 0, stream>>>(bsum, NB1);
    scan3_kernel<<<NB1, 256, 0, stream>>>(cnt, bsum, off, cur, N_CNT, E);

    // 3. fill (int CSR) fused with w0 = dis*x0 conversion
    fill_w0_kernel<<<gE + gW, B, 0, stream>>>(row, col, cur, csr, E, gE,
                                              embU, embIadj, dis, (ushort4*)w0);

    // 4. layers 1..3 (+ distributed verbatim copies, + s3 in layer 3)
    gatherw_kernel<<<gGather, B, 0, stream>>>(off, csr, (const uint32_t*)w0, (uint4*)w1,
        dis2, E, nullptr, nullptr, nullptr, embU, cu, 0, U_CNT);
    gatherw_kernel<<<gGather, B, 0, stream>>>(off, csr, (const uint32_t*)w1, (uint4*)w2,
        dis2, E, nullptr, nullptr, nullptr, embIadj, ciadj, U_CNT, N_CNT);
    gatherw_kernel<<<gGather, B, 0, stream>>>(off, csr, (const uint32_t*)w2, (uint4*)w3,
        dis2, E, (u32x4*)s3, (const u32x4*)w1, (const u32x4*)w2, nullptr, nullptr, 0, 0);

    // 5. layer 4 + finalize
    final_kernel<<<gGather, B, 0, stream>>>(off, csr, (const uint32_t*)w3, (const u32x4*)s3,
        embU, embIadj, dis, rdis, finU, finIadj, E);
}

// Round 9
// 701.952 us; speedup vs baseline: 1.0481x; 1.0481x over previous
//
#include <hip/hip_runtime.h>
#include <stdint.h>

#define U_CNT 300000
#define I_CNT 200000
#define N_CNT 500000
#define DIM 64
#define SCAN_CHUNK 1024
#define NB1 ((N_CNT + SCAN_CHUNK - 1) / SCAN_CHUNK)   // 489

typedef unsigned short bf16_t;
typedef float    f32x4 __attribute__((ext_vector_type(4)));
typedef uint32_t u32x4 __attribute__((ext_vector_type(4)));

__device__ __forceinline__ float lof(uint32_t u) { return __uint_as_float(u << 16); }
__device__ __forceinline__ float hif(uint32_t u) { return __uint_as_float(u & 0xFFFF0000u); }
__device__ __forceinline__ uint32_t rnd_bf(float f) {
    uint32_t u = __float_as_uint(f);
    return u + (0x7FFFu + ((u >> 16) & 1u));      // rne, still in high bits
}
__device__ __forceinline__ uint32_t packbf(float lo, float hi) {
    return (rnd_bf(lo) >> 16) | (rnd_bf(hi) & 0xFFFF0000u);
}
__device__ __forceinline__ bf16_t f2b(float f) { return (bf16_t)(rnd_bf(f) >> 16); }

// ---------------- degree ----------------

__global__ void deg_cnt_kernel(const int* __restrict__ col, int* __restrict__ cnt, int E) {
    int e = blockIdx.x * blockDim.x + threadIdx.x;
    if (e < E) atomicAdd(&cnt[col[e]], 1);
}

// ---------------- scan1 + normalization arrays ----------------

__global__ void scan1_dis_kernel(const int* __restrict__ cnt, int* __restrict__ bsum,
                                 float* __restrict__ dis, float* __restrict__ dis2,
                                 float* __restrict__ rdis, int n) {
    __shared__ int lds[256];
    int t = threadIdx.x;
    int i = blockIdx.x * SCAN_CHUNK + t * 4;
    int4 v = make_int4(0, 0, 0, 0);
    if (i + 3 < n) v = *(const int4*)(cnt + i);
    else {
        if (i     < n) v.x = cnt[i];
        if (i + 1 < n) v.y = cnt[i + 1];
        if (i + 2 < n) v.z = cnt[i + 2];
        if (i + 3 < n) v.w = cnt[i + 3];
    }
    if (i + 3 < n) {
        int dd[4] = {v.x, v.y, v.z, v.w};
        f32x4 fd, f2, fr;
        #pragma unroll
        for (int k = 0; k < 4; k++) {
            float d = (float)dd[k];
            float s = dd[k] > 0 ? rsqrtf(d) : 0.0f;
            fd[k] = s; f2[k] = s * s; fr[k] = d * s;
        }
        *(f32x4*)(dis + i) = fd;
        *(f32x4*)(dis2 + i) = f2;
        *(f32x4*)(rdis + i) = fr;
    } else {
        for (int k = 0; k < 4 && i + k < n; k++) {
            int d = (&v.x)[k];
            float s = d > 0 ? rsqrtf((float)d) : 0.0f;
            dis[i + k] = s; dis2[i + k] = s * s; rdis[i + k] = (float)d * s;
        }
    }
    lds[t] = v.x + v.y + v.z + v.w;
    __syncthreads();
    for (int o = 128; o > 0; o >>= 1) {
        if (t < o) lds[t] += lds[t + o];
        __syncthreads();
    }
    if (t == 0) bsum[blockIdx.x] = lds[0];
}

__global__ void scan2_kernel(int* __restrict__ bsum, int nb) {
    __shared__ int lds[512];
    int t = threadIdx.x;
    int v = (t < nb) ? bsum[t] : 0;
    lds[t] = v;
    __syncthreads();
    for (int o = 1; o < 512; o <<= 1) {
        int a = lds[t] + ((t >= o) ? lds[t - o] : 0);
        __syncthreads();
        lds[t] = a;
        __syncthreads();
    }
    if (t < nb) bsum[t] = lds[t] - v;
}

__global__ void scan3_kernel(const int* __restrict__ cnt, const int* __restrict__ bsum,
                             int* __restrict__ off, int* __restrict__ cur, int n, int E) {
    __shared__ int lds[256];
    int t = threadIdx.x;
    int i = blockIdx.x * SCAN_CHUNK + t * 4;
    int4 v = make_int4(0, 0, 0, 0);
    if (i + 3 < n) v = *(const int4*)(cnt + i);
    else {
        if (i     < n) v.x = cnt[i];
        if (i + 1 < n) v.y = cnt[i + 1];
        if (i + 2 < n) v.z = cnt[i + 2];
        if (i + 3 < n) v.w = cnt[i + 3];
    }
    int s = v.x + v.y + v.z + v.w;
    lds[t] = s;
    __syncthreads();
    for (int o = 1; o < 256; o <<= 1) {
        int a = lds[t] + ((t >= o) ? lds[t - o] : 0);
        __syncthreads();
        lds[t] = a;
        __syncthreads();
    }
    int ex = lds[t] - s + bsum[blockIdx.x];
    int o0 = ex, o1 = ex + v.x, o2 = o1 + v.y, o3 = o2 + v.z;
    if (i     < n) { off[i]     = o0; cur[i]     = o0; }
    if (i + 1 < n) { off[i + 1] = o1; cur[i + 1] = o1; }
    if (i + 2 < n) { off[i + 2] = o2; cur[i + 2] = o2; }
    if (i + 3 < n) { off[i + 3] = o3; cur[i + 3] = o3; }
    if (i == n - 4) off[n] = E;   // N_CNT % 4 == 0
}

// ---------------- fill (int CSR) — ALONE, so csr scatters merge in L2 ----------------

__global__ void fill_kernel(const int* __restrict__ row, const int* __restrict__ col,
                            int* __restrict__ cur, int* __restrict__ csr, int E) {
    int e = blockIdx.x * blockDim.x + threadIdx.x;
    if (e < E) {
        int r = row[e], c = col[e];
        int p = atomicAdd(&cur[c], 1);
        csr[p] = r;
    }
}

// ---------------- w0 = dis * x0, bf16 (separate streaming kernel) ----------------

__global__ void w0_kernel(const float* __restrict__ embU, const float* __restrict__ embIadj,
                          const float* __restrict__ dis, ushort4* __restrict__ w0) {
    int q = blockIdx.x * blockDim.x + threadIdx.x;   // float4 index, exactly N_CNT*16 total
    int node = q >> 4;
    const float* src = (node < U_CNT ? embU : embIadj);
    f32x4 v = *((const f32x4*)src + q);
    float dn = dis[node];
    ushort4 w;
    w.x = f2b(v[0] * dn); w.y = f2b(v[1] * dn);
    w.z = f2b(v[2] * dn); w.w = f2b(v[3] * dn);
    w0[q] = w;
}

// ---------------- gather propagation (layers 1..3) ----------------
// w_out[c] = dis2[c] * sum_{r in N(c)} w_in[r]   (8 lanes/node, uint4 = 8 bf16)
// Optional: s_out = w1 + w2 + w_out (bf16, nt)  [layer 3]
// Optional: verbatim emb copy for nodes in [cpyLo, cpyHi)  [layers 1, 2]
__global__ __launch_bounds__(256) void gatherw_kernel(
        const int* __restrict__ off, const int* __restrict__ csr,
        const uint32_t* __restrict__ w_in, uint4* __restrict__ w_out,
        const float* __restrict__ dis2, int nE,
        u32x4* __restrict__ s_out, const u32x4* __restrict__ w1, const u32x4* __restrict__ w2,
        const float* __restrict__ cpySrc, float* __restrict__ cpyDst, int cpyLo, int cpyHi) {
    int lane = threadIdx.x & 63;
    int sub  = lane & 7;
    int n = blockIdx.x * 32 + (threadIdx.x >> 6) * 8 + (lane >> 3);  // N_CNT % 32 == 0
    int s = off[n], e = off[n + 1];
    const uint4* xv = (const uint4*)w_in;
    size_t nodeOff = ((size_t)n << 3) + sub;

    u32x4 u1 = {0, 0, 0, 0}, u2 = {0, 0, 0, 0};
    if (s_out) {
        u1 = __builtin_nontemporal_load(w1 + nodeOff);
        u2 = __builtin_nontemporal_load(w2 + nodeOff);
    }
    f32x4 cb0, cb1;
    bool doCpy = (cpyDst != nullptr) && (n >= cpyLo) && (n < cpyHi);
    size_t fbase = ((size_t)n << 6) + (size_t)sub * 8;
    if (doCpy) {
        cb0 = __builtin_nontemporal_load((const f32x4*)(cpySrc + fbase));
        cb1 = __builtin_nontemporal_load((const f32x4*)(cpySrc + fbase + 4));
    }

    float a0 = 0, a1 = 0, a2 = 0, a3 = 0, a4 = 0, a5 = 0, a6 = 0, a7 = 0;

    int i0 = s;
    int ca = csr[(i0     < nE) ? i0     : (nE - 1)];
    int cb = csr[(i0 + 1 < nE) ? i0 + 1 : (nE - 1)];
    float na = (i0     < e) ? 1.0f : 0.0f;
    float nb = (i0 + 1 < e) ? 1.0f : 0.0f;
    int   ra = (i0     < e) ? ca : 0;
    int   rb = (i0 + 1 < e) ? cb : 0;
    uint4 va = xv[((size_t)ra << 3) + sub];
    uint4 vb = xv[((size_t)rb << 3) + sub];
    int i1 = i0 + 2;
    int qa = csr[(i1     < nE) ? i1     : (nE - 1)];
    int qb = csr[(i1 + 1 < nE) ? i1 + 1 : (nE - 1)];

    while (i0 < e) {
        float ma = (i1     < e) ? 1.0f : 0.0f;
        float mb = (i1 + 1 < e) ? 1.0f : 0.0f;
        int   sa = (i1     < e) ? qa : 0;
        int   sb = (i1 + 1 < e) ? qb : 0;
        uint4 wa = xv[((size_t)sa << 3) + sub];
        uint4 wb = xv[((size_t)sb << 3) + sub];
        int i2 = i1 + 2;
        qa = csr[(i2     < nE) ? i2     : (nE - 1)];
        qb = csr[(i2 + 1 < nE) ? i2 + 1 : (nE - 1)];
        a0 = fmaf(na, lof(va.x), a0); a1 = fmaf(na, hif(va.x), a1);
        a2 = fmaf(na, lof(va.y), a2); a3 = fmaf(na, hif(va.y), a3);
        a4 = fmaf(na, lof(va.z), a4); a5 = fmaf(na, hif(va.z), a5);
        a6 = fmaf(na, lof(va.w), a6); a7 = fmaf(na, hif(va.w), a7);
        a0 = fmaf(nb, lof(vb.x), a0); a1 = fmaf(nb, hif(vb.x), a1);
        a2 = fmaf(nb, lof(vb.y), a2); a3 = fmaf(nb, hif(vb.y), a3);
        a4 = fmaf(nb, lof(vb.z), a4); a5 = fmaf(nb, hif(vb.z), a5);
        a6 = fmaf(nb, lof(vb.w), a6); a7 = fmaf(nb, hif(vb.w), a7);
        va = wa; vb = wb; na = ma; nb = mb;
        i0 = i1; i1 = i2;
    }

    float d2 = dis2[n];
    a0 *= d2; a1 *= d2; a2 *= d2; a3 *= d2;
    a4 *= d2; a5 *= d2; a6 *= d2; a7 *= d2;

    uint4 w;
    w.x = packbf(a0, a1); w.y = packbf(a2, a3);
    w.z = packbf(a4, a5); w.w = packbf(a6, a7);
    w_out[nodeOff] = w;   // cached: gather source of next layer

    if (s_out) {
        u32x4 sv;
        sv[0] = packbf(lof(u1[0]) + lof(u2[0]) + a0, hif(u1[0]) + hif(u2[0]) + a1);
        sv[1] = packbf(lof(u1[1]) + lof(u2[1]) + a2, hif(u1[1]) + hif(u2[1]) + a3);
        sv[2] = packbf(lof(u1[2]) + lof(u2[2]) + a4, hif(u1[2]) + hif(u2[2]) + a5);
        sv[3] = packbf(lof(u1[3]) + lof(u2[3]) + a6, hif(u1[3]) + hif(u2[3]) + a7);
        __builtin_nontemporal_store(sv, s_out + nodeOff);
    }
    if (doCpy) {
        __builtin_nontemporal_store(cb0, (f32x4*)(cpyDst + fbase));
        __builtin_nontemporal_store(cb1, (f32x4*)(cpyDst + fbase + 4));
    }
}

// ---------------- final: gather layer 4 + finalize ----------------
// t4 = sum w3[r]; y4 = dis[c]*t4; fin = (emb + rdis*s3 + y4)/25

__global__ __launch_bounds__(256) void final_kernel(
        const int* __restrict__ off, const int* __restrict__ csr,
        const uint32_t* __restrict__ w3, const u32x4* __restrict__ s3,
        const float* __restrict__ embU, const float* __restrict__ embIadj,
        const float* __restrict__ dis, const float* __restrict__ rdis,
        float* __restrict__ finU, float* __restrict__ finIadj, int nE) {
    int lane = threadIdx.x & 63;
    int sub  = lane & 7;
    int n = blockIdx.x * 32 + (threadIdx.x >> 6) * 8 + (lane >> 3);
    int s = off[n], e = off[n + 1];
    const uint4* xv = (const uint4*)w3;
    size_t nodeOff = ((size_t)n << 3) + sub;
    size_t fbase   = ((size_t)n << 6) + (size_t)sub * 8;

    const float* embP = (n < U_CNT ? embU : embIadj) + fbase;
    float*       finP = (n < U_CNT ? finU : finIadj) + fbase;
    f32x4 b0 = __builtin_nontemporal_load((const f32x4*)embP);
    f32x4 b1 = __builtin_nontemporal_load((const f32x4*)(embP + 4));
    u32x4 u3 = __builtin_nontemporal_load(s3 + nodeOff);

    float a0 = 0, a1 = 0, a2 = 0, a3 = 0, a4 = 0, a5 = 0, a6 = 0, a7 = 0;

    int i0 = s;
    int ca = csr[(i0     < nE) ? i0     : (nE - 1)];
    int cb = csr[(i0 + 1 < nE) ? i0 + 1 : (nE - 1)];
    float na = (i0     < e) ? 1.0f : 0.0f;
    float nb = (i0 + 1 < e) ? 1.0f : 0.0f;
    int   ra = (i0     < e) ? ca : 0;
    int   rb = (i0 + 1 < e) ? cb : 0;
    uint4 va = xv[((size_t)ra << 3) + sub];
    uint4 vb = xv[((size_t)rb << 3) + sub];
    int i1 = i0 + 2;
    int qa = csr[(i1     < nE) ? i1     : (nE - 1)];
    int qb = csr[(i1 + 1 < nE) ? i1 + 1 : (nE - 1)];

    while (i0 < e) {
        float ma = (i1     < e) ? 1.0f : 0.0f;
        float mb = (i1 + 1 < e) ? 1.0f : 0.0f;
        int   sa = (i1     < e) ? qa : 0;
        int   sb = (i1 + 1 < e) ? qb : 0;
        uint4 wa = xv[((size_t)sa << 3) + sub];
        uint4 wb = xv[((size_t)sb << 3) + sub];
        int i2 = i1 + 2;
        qa = csr[(i2     < nE) ? i2     : (nE - 1)];
        qb = csr[(i2 + 1 < nE) ? i2 + 1 : (nE - 1)];
        a0 = fmaf(na, lof(va.x), a0); a1 = fmaf(na, hif(va.x), a1);
        a2 = fmaf(na, lof(va.y), a2); a3 = fmaf(na, hif(va.y), a3);
        a4 = fmaf(na, lof(va.z), a4); a5 = fmaf(na, hif(va.z), a5);
        a6 = fmaf(na, lof(va.w), a6); a7 = fmaf(na, hif(va.w), a7);
        a0 = fmaf(nb, lof(vb.x), a0); a1 = fmaf(nb, hif(vb.x), a1);
        a2 = fmaf(nb, lof(vb.y), a2); a3 = fmaf(nb, hif(vb.y), a3);
        a4 = fmaf(nb, lof(vb.z), a4); a5 = fmaf(nb, hif(vb.z), a5);
        a6 = fmaf(nb, lof(vb.w), a6); a7 = fmaf(nb, hif(vb.w), a7);
        va = wa; vb = wb; na = ma; nb = mb;
        i0 = i1; i1 = i2;
    }

    float dn = dis[n];
    float rd = rdis[n];
    const float k = 1.0f / 25.0f;
    f32x4 r0, r1;
    r0[0] = (b0[0] + rd * lof(u3[0]) + dn * a0) * k;
    r0[1] = (b0[1] + rd * hif(u3[0]) + dn * a1) * k;
    r0[2] = (b0[2] + rd * lof(u3[1]) + dn * a2) * k;
    r0[3] = (b0[3] + rd * hif(u3[1]) + dn * a3) * k;
    r1[0] = (b1[0] + rd * lof(u3[2]) + dn * a4) * k;
    r1[1] = (b1[1] + rd * hif(u3[2]) + dn * a5) * k;
    r1[2] = (b1[2] + rd * lof(u3[3]) + dn * a6) * k;
    r1[3] = (b1[3] + rd * hif(u3[3]) + dn * a7) * k;
    __builtin_nontemporal_store(r0, (f32x4*)finP);
    __builtin_nontemporal_store(r1, (f32x4*)(finP + 4));
}

// ---------------- host ----------------

extern "C" void kernel_launch(void* const* d_in, const int* in_sizes, int n_in,
                              void* d_out, int out_size, void* d_ws, size_t ws_size,
                              hipStream_t stream) {
    const int*   edge = (const int*)d_in[0];
    const float* embU = (const float*)d_in[1];
    const float* embI = (const float*)d_in[2];
    const int E = in_sizes[0] / 2;
    const int* row = edge;
    const int* col = edge + E;

    float* out  = (float*)d_out;
    float* finU = out;
    float* cu   = out + (size_t)U_CNT * DIM;
    float* finI = out + (size_t)2 * U_CNT * DIM;
    float* ci   = finI + (size_t)I_CNT * DIM;

    // workspace carve-up
    const size_t XB = (size_t)N_CNT * DIM * sizeof(bf16_t);   // 64 MB
    char* ws = (char*)d_ws;
    size_t p = 0;
    bf16_t* w0 = (bf16_t*)(ws + p); p += XB;
    bf16_t* w1 = (bf16_t*)(ws + p); p += XB;
    bf16_t* w2 = (bf16_t*)(ws + p); p += XB;
    bf16_t* w3 = (bf16_t*)(ws + p); p += XB;
    bf16_t* s3 = (bf16_t*)(ws + p); p += XB;
    int*   cnt  = (int*)(ws + p);   p += ((size_t)N_CNT + 4) * sizeof(int);
    int*   off  = (int*)(ws + p);   p += ((size_t)N_CNT + 4) * sizeof(int);
    int*   cur  = (int*)(ws + p);   p += ((size_t)N_CNT + 4) * sizeof(int);
    float* dis  = (float*)(ws + p); p += ((size_t)N_CNT + 4) * sizeof(float);
    float* dis2 = (float*)(ws + p); p += ((size_t)N_CNT + 4) * sizeof(float);
    float* rdis = (float*)(ws + p); p += ((size_t)N_CNT + 4) * sizeof(float);
    int*   bsum = (int*)(ws + p);   p += 1024 * sizeof(int);
    int*   csr  = (int*)(ws + p);   p += (size_t)E * sizeof(int);               // 10 MB

    const float* embIadj = embI - (size_t)U_CNT * DIM;
    float* finIadj = finI - (size_t)U_CNT * DIM;
    float* ciadj   = ci   - (size_t)U_CNT * DIM;

    const int B = 256;
    const int gE  = (E + B - 1) / B;
    const int gW  = N_CNT * 16 / B;     // 31250 float4-blocks, exact
    const int gGather = N_CNT / 32;     // 15625, exact

    // 1. degree
    hipMemsetAsync(cnt, 0, (size_t)N_CNT * sizeof(int), stream);
    deg_cnt_kernel<<<gE, B, 0, stream>>>(col, cnt, E);

    // 2. scan + normalization arrays
    scan1_dis_kernel<<<NB1, 256, 0, stream>>>(cnt, bsum, dis, dis2, rdis, N_CNT);
    scan2_kernel<<<1, 512, 0, stream>>>(bsum, NB1);
    scan3_kernel<<<NB1, 256, 0, stream>>>(cnt, bsum, off, cur, N_CNT, E);

    // 3. fill ALONE (csr scatters merge in L2), then the w0 stream
    fill_kernel<<<gE, B, 0, stream>>>(row, col, cur, csr, E);
    w0_kernel<<<gW, B, 0, stream>>>(embU, embIadj, dis, (ushort4*)w0);

    // 4. layers 1..3 (+ distributed verbatim copies, + s3 in layer 3)
    gatherw_kernel<<<gGather, B, 0, stream>>>(off, csr, (const uint32_t*)w0, (uint4*)w1,
        dis2, E, nullptr, nullptr, nullptr, embU, cu, 0, U_CNT);
    gatherw_kernel<<<gGather, B, 0, stream>>>(off, csr, (const uint32_t*)w1, (uint4*)w2,
        dis2, E, nullptr, nullptr, nullptr, embIadj, ciadj, U_CNT, N_CNT);
    gatherw_kernel<<<gGather, B, 0, stream>>>(off, csr, (const uint32_t*)w2, (uint4*)w3,
        dis2, E, (u32x4*)s3, (const u32x4*)w1, (const u32x4*)w2, nullptr, nullptr, 0, 0);

    // 5. layer 4 + finalize
    final_kernel<<<gGather, B, 0, stream>>>(off, csr, (const uint32_t*)w3, (const u32x4*)s3,
        embU, embIadj, dis, rdis, finU, finIadj, E);
}

// Round 10
// 628.034 us; speedup vs baseline: 1.1714x; 1.1177x over previous
//
#include <hip/hip_runtime.h>
#include <stdint.h>

#define U_CNT 300000
#define I_CNT 200000
#define N_CNT 500000
#define DIM 64
#define SCAN_CHUNK 1024
#define NB1 ((N_CNT + SCAN_CHUNK - 1) / SCAN_CHUNK)   // 489
#define NPASS 4
#define BUCKET (N_CNT / NPASS)                        // 125000

typedef unsigned short bf16_t;
typedef float    f32x4 __attribute__((ext_vector_type(4)));
typedef uint32_t u32x4 __attribute__((ext_vector_type(4)));

__device__ __forceinline__ float lof(uint32_t u) { return __uint_as_float(u << 16); }
__device__ __forceinline__ float hif(uint32_t u) { return __uint_as_float(u & 0xFFFF0000u); }
__device__ __forceinline__ uint32_t rnd_bf(float f) {
    uint32_t u = __float_as_uint(f);
    return u + (0x7FFFu + ((u >> 16) & 1u));      // rne, still in high bits
}
__device__ __forceinline__ uint32_t packbf(float lo, float hi) {
    return (rnd_bf(lo) >> 16) | (rnd_bf(hi) & 0xFFFF0000u);
}
__device__ __forceinline__ bf16_t f2b(float f) { return (bf16_t)(rnd_bf(f) >> 16); }

// ---------------- degree ----------------

__global__ void deg_cnt_kernel(const int* __restrict__ col, int* __restrict__ cnt, int E) {
    int e = blockIdx.x * blockDim.x + threadIdx.x;
    if (e < E) atomicAdd(&cnt[col[e]], 1);
}

// ---------------- scan1 + normalization arrays ----------------

__global__ void scan1_dis_kernel(const int* __restrict__ cnt, int* __restrict__ bsum,
                                 float* __restrict__ dis, float* __restrict__ dis2,
                                 float* __restrict__ rdis, int n) {
    __shared__ int lds[256];
    int t = threadIdx.x;
    int i = blockIdx.x * SCAN_CHUNK + t * 4;
    int4 v = make_int4(0, 0, 0, 0);
    if (i + 3 < n) v = *(const int4*)(cnt + i);
    else {
        if (i     < n) v.x = cnt[i];
        if (i + 1 < n) v.y = cnt[i + 1];
        if (i + 2 < n) v.z = cnt[i + 2];
        if (i + 3 < n) v.w = cnt[i + 3];
    }
    if (i + 3 < n) {
        int dd[4] = {v.x, v.y, v.z, v.w};
        f32x4 fd, f2, fr;
        #pragma unroll
        for (int k = 0; k < 4; k++) {
            float d = (float)dd[k];
            float s = dd[k] > 0 ? rsqrtf(d) : 0.0f;
            fd[k] = s; f2[k] = s * s; fr[k] = d * s;
        }
        *(f32x4*)(dis + i) = fd;
        *(f32x4*)(dis2 + i) = f2;
        *(f32x4*)(rdis + i) = fr;
    } else {
        for (int k = 0; k < 4 && i + k < n; k++) {
            int d = (&v.x)[k];
            float s = d > 0 ? rsqrtf((float)d) : 0.0f;
            dis[i + k] = s; dis2[i + k] = s * s; rdis[i + k] = (float)d * s;
        }
    }
    lds[t] = v.x + v.y + v.z + v.w;
    __syncthreads();
    for (int o = 128; o > 0; o >>= 1) {
        if (t < o) lds[t] += lds[t + o];
        __syncthreads();
    }
    if (t == 0) bsum[blockIdx.x] = lds[0];
}

__global__ void scan2_kernel(int* __restrict__ bsum, int nb) {
    __shared__ int lds[512];
    int t = threadIdx.x;
    int v = (t < nb) ? bsum[t] : 0;
    lds[t] = v;
    __syncthreads();
    for (int o = 1; o < 512; o <<= 1) {
        int a = lds[t] + ((t >= o) ? lds[t - o] : 0);
        __syncthreads();
        lds[t] = a;
        __syncthreads();
    }
    if (t < nb) bsum[t] = lds[t] - v;
}

__global__ void scan3_kernel(const int* __restrict__ cnt, const int* __restrict__ bsum,
                             int* __restrict__ off, int* __restrict__ cur, int n, int E) {
    __shared__ int lds[256];
    int t = threadIdx.x;
    int i = blockIdx.x * SCAN_CHUNK + t * 4;
    int4 v = make_int4(0, 0, 0, 0);
    if (i + 3 < n) v = *(const int4*)(cnt + i);
    else {
        if (i     < n) v.x = cnt[i];
        if (i + 1 < n) v.y = cnt[i + 1];
        if (i + 2 < n) v.z = cnt[i + 2];
        if (i + 3 < n) v.w = cnt[i + 3];
    }
    int s = v.x + v.y + v.z + v.w;
    lds[t] = s;
    __syncthreads();
    for (int o = 1; o < 256; o <<= 1) {
        int a = lds[t] + ((t >= o) ? lds[t - o] : 0);
        __syncthreads();
        lds[t] = a;
        __syncthreads();
    }
    int ex = lds[t] - s + bsum[blockIdx.x];
    int o0 = ex, o1 = ex + v.x, o2 = o1 + v.y, o3 = o2 + v.z;
    if (i     < n) { off[i]     = o0; cur[i]     = o0; }
    if (i + 1 < n) { off[i + 1] = o1; cur[i + 1] = o1; }
    if (i + 2 < n) { off[i + 2] = o2; cur[i + 2] = o2; }
    if (i + 3 < n) { off[i + 3] = o3; cur[i + 3] = o3; }
    if (i == n - 4) off[n] = E;   // N_CNT % 4 == 0
}

// ---------------- bucketed fill: only dests in [lo, hi) this pass ----------------
// csr write window per pass ~2.5 MB -> merges in per-XCD L2 before eviction.

__global__ void fill_bucket_kernel(const int* __restrict__ row, const int* __restrict__ col,
                                   int* __restrict__ cur, int* __restrict__ csr, int E,
                                   int lo, int hi) {
    int e = blockIdx.x * blockDim.x + threadIdx.x;
    if (e < E) {
        int c = col[e];
        if (c >= lo && c < hi) {
            int p = atomicAdd(&cur[c], 1);
            csr[p] = row[e];
        }
    }
}

// ---------------- w0 = dis * x0, bf16 ----------------

__global__ void w0_kernel(const float* __restrict__ embU, const float* __restrict__ embIadj,
                          const float* __restrict__ dis, ushort4* __restrict__ w0) {
    int q = blockIdx.x * blockDim.x + threadIdx.x;   // float4 index, exactly N_CNT*16 total
    int node = q >> 4;
    const float* src = (node < U_CNT ? embU : embIadj);
    f32x4 v = *((const f32x4*)src + q);
    float dn = dis[node];
    ushort4 w;
    w.x = f2b(v[0] * dn); w.y = f2b(v[1] * dn);
    w.z = f2b(v[2] * dn); w.w = f2b(v[3] * dn);
    w0[q] = w;
}

// ---------------- gather propagation (layers 1..3) ----------------
__global__ __launch_bounds__(256) void gatherw_kernel(
        const int* __restrict__ off, const int* __restrict__ csr,
        const uint32_t* __restrict__ w_in, uint4* __restrict__ w_out,
        const float* __restrict__ dis2, int nE,
        u32x4* __restrict__ s_out, const u32x4* __restrict__ w1, const u32x4* __restrict__ w2,
        const float* __restrict__ cpySrc, float* __restrict__ cpyDst, int cpyLo, int cpyHi) {
    int lane = threadIdx.x & 63;
    int sub  = lane & 7;
    int n = blockIdx.x * 32 + (threadIdx.x >> 6) * 8 + (lane >> 3);  // N_CNT % 32 == 0
    int s = off[n], e = off[n + 1];
    const uint4* xv = (const uint4*)w_in;
    size_t nodeOff = ((size_t)n << 3) + sub;

    u32x4 u1 = {0, 0, 0, 0}, u2 = {0, 0, 0, 0};
    if (s_out) {
        u1 = __builtin_nontemporal_load(w1 + nodeOff);
        u2 = __builtin_nontemporal_load(w2 + nodeOff);
    }
    f32x4 cb0, cb1;
    bool doCpy = (cpyDst != nullptr) && (n >= cpyLo) && (n < cpyHi);
    size_t fbase = ((size_t)n << 6) + (size_t)sub * 8;
    if (doCpy) {
        cb0 = __builtin_nontemporal_load((const f32x4*)(cpySrc + fbase));
        cb1 = __builtin_nontemporal_load((const f32x4*)(cpySrc + fbase + 4));
    }

    float a0 = 0, a1 = 0, a2 = 0, a3 = 0, a4 = 0, a5 = 0, a6 = 0, a7 = 0;

    int i0 = s;
    int ca = csr[(i0     < nE) ? i0     : (nE - 1)];
    int cb = csr[(i0 + 1 < nE) ? i0 + 1 : (nE - 1)];
    float na = (i0     < e) ? 1.0f : 0.0f;
    float nb = (i0 + 1 < e) ? 1.0f : 0.0f;
    int   ra = (i0     < e) ? ca : 0;
    int   rb = (i0 + 1 < e) ? cb : 0;
    uint4 va = xv[((size_t)ra << 3) + sub];
    uint4 vb = xv[((size_t)rb << 3) + sub];
    int i1 = i0 + 2;
    int qa = csr[(i1     < nE) ? i1     : (nE - 1)];
    int qb = csr[(i1 + 1 < nE) ? i1 + 1 : (nE - 1)];

    while (i0 < e) {
        float ma = (i1     < e) ? 1.0f : 0.0f;
        float mb = (i1 + 1 < e) ? 1.0f : 0.0f;
        int   sa = (i1     < e) ? qa : 0;
        int   sb = (i1 + 1 < e) ? qb : 0;
        uint4 wa = xv[((size_t)sa << 3) + sub];
        uint4 wb = xv[((size_t)sb << 3) + sub];
        int i2 = i1 + 2;
        qa = csr[(i2     < nE) ? i2     : (nE - 1)];
        qb = csr[(i2 + 1 < nE) ? i2 + 1 : (nE - 1)];
        a0 = fmaf(na, lof(va.x), a0); a1 = fmaf(na, hif(va.x), a1);
        a2 = fmaf(na, lof(va.y), a2); a3 = fmaf(na, hif(va.y), a3);
        a4 = fmaf(na, lof(va.z), a4); a5 = fmaf(na, hif(va.z), a5);
        a6 = fmaf(na, lof(va.w), a6); a7 = fmaf(na, hif(va.w), a7);
        a0 = fmaf(nb, lof(vb.x), a0); a1 = fmaf(nb, hif(vb.x), a1);
        a2 = fmaf(nb, lof(vb.y), a2); a3 = fmaf(nb, hif(vb.y), a3);
        a4 = fmaf(nb, lof(vb.z), a4); a5 = fmaf(nb, hif(vb.z), a5);
        a6 = fmaf(nb, lof(vb.w), a6); a7 = fmaf(nb, hif(vb.w), a7);
        va = wa; vb = wb; na = ma; nb = mb;
        i0 = i1; i1 = i2;
    }

    float d2 = dis2[n];
    a0 *= d2; a1 *= d2; a2 *= d2; a3 *= d2;
    a4 *= d2; a5 *= d2; a6 *= d2; a7 *= d2;

    uint4 w;
    w.x = packbf(a0, a1); w.y = packbf(a2, a3);
    w.z = packbf(a4, a5); w.w = packbf(a6, a7);
    w_out[nodeOff] = w;   // cached: gather source of next layer

    if (s_out) {
        u32x4 sv;
        sv[0] = packbf(lof(u1[0]) + lof(u2[0]) + a0, hif(u1[0]) + hif(u2[0]) + a1);
        sv[1] = packbf(lof(u1[1]) + lof(u2[1]) + a2, hif(u1[1]) + hif(u2[1]) + a3);
        sv[2] = packbf(lof(u1[2]) + lof(u2[2]) + a4, hif(u1[2]) + hif(u2[2]) + a5);
        sv[3] = packbf(lof(u1[3]) + lof(u2[3]) + a6, hif(u1[3]) + hif(u2[3]) + a7);
        __builtin_nontemporal_store(sv, s_out + nodeOff);
    }
    if (doCpy) {
        __builtin_nontemporal_store(cb0, (f32x4*)(cpyDst + fbase));
        __builtin_nontemporal_store(cb1, (f32x4*)(cpyDst + fbase + 4));
    }
}

// ---------------- final: gather layer 4 + finalize ----------------

__global__ __launch_bounds__(256) void final_kernel(
        const int* __restrict__ off, const int* __restrict__ csr,
        const uint32_t* __restrict__ w3, const u32x4* __restrict__ s3,
        const float* __restrict__ embU, const float* __restrict__ embIadj,
        const float* __restrict__ dis, const float* __restrict__ rdis,
        float* __restrict__ finU, float* __restrict__ finIadj, int nE) {
    int lane = threadIdx.x & 63;
    int sub  = lane & 7;
    int n = blockIdx.x * 32 + (threadIdx.x >> 6) * 8 + (lane >> 3);
    int s = off[n], e = off[n + 1];
    const uint4* xv = (const uint4*)w3;
    size_t nodeOff = ((size_t)n << 3) + sub;
    size_t fbase   = ((size_t)n << 6) + (size_t)sub * 8;

    const float* embP = (n < U_CNT ? embU : embIadj) + fbase;
    float*       finP = (n < U_CNT ? finU : finIadj) + fbase;
    f32x4 b0 = __builtin_nontemporal_load((const f32x4*)embP);
    f32x4 b1 = __builtin_nontemporal_load((const f32x4*)(embP + 4));
    u32x4 u3 = __builtin_nontemporal_load(s3 + nodeOff);

    float a0 = 0, a1 = 0, a2 = 0, a3 = 0, a4 = 0, a5 = 0, a6 = 0, a7 = 0;

    int i0 = s;
    int ca = csr[(i0     < nE) ? i0     : (nE - 1)];
    int cb = csr[(i0 + 1 < nE) ? i0 + 1 : (nE - 1)];
    float na = (i0     < e) ? 1.0f : 0.0f;
    float nb = (i0 + 1 < e) ? 1.0f : 0.0f;
    int   ra = (i0     < e) ? ca : 0;
    int   rb = (i0 + 1 < e) ? cb : 0;
    uint4 va = xv[((size_t)ra << 3) + sub];
    uint4 vb = xv[((size_t)rb << 3) + sub];
    int i1 = i0 + 2;
    int qa = csr[(i1     < nE) ? i1     : (nE - 1)];
    int qb = csr[(i1 + 1 < nE) ? i1 + 1 : (nE - 1)];

    while (i0 < e) {
        float ma = (i1     < e) ? 1.0f : 0.0f;
        float mb = (i1 + 1 < e) ? 1.0f : 0.0f;
        int   sa = (i1     < e) ? qa : 0;
        int   sb = (i1 + 1 < e) ? qb : 0;
        uint4 wa = xv[((size_t)sa << 3) + sub];
        uint4 wb = xv[((size_t)sb << 3) + sub];
        int i2 = i1 + 2;
        qa = csr[(i2     < nE) ? i2     : (nE - 1)];
        qb = csr[(i2 + 1 < nE) ? i2 + 1 : (nE - 1)];
        a0 = fmaf(na, lof(va.x), a0); a1 = fmaf(na, hif(va.x), a1);
        a2 = fmaf(na, lof(va.y), a2); a3 = fmaf(na, hif(va.y), a3);
        a4 = fmaf(na, lof(va.z), a4); a5 = fmaf(na, hif(va.z), a5);
        a6 = fmaf(na, lof(va.w), a6); a7 = fmaf(na, hif(va.w), a7);
        a0 = fmaf(nb, lof(vb.x), a0); a1 = fmaf(nb, hif(vb.x), a1);
        a2 = fmaf(nb, lof(vb.y), a2); a3 = fmaf(nb, hif(vb.y), a3);
        a4 = fmaf(nb, lof(vb.z), a4); a5 = fmaf(nb, hif(vb.z), a5);
        a6 = fmaf(nb, lof(vb.w), a6); a7 = fmaf(nb, hif(vb.w), a7);
        va = wa; vb = wb; na = ma; nb = mb;
        i0 = i1; i1 = i2;
    }

    float dn = dis[n];
    float rd = rdis[n];
    const float k = 1.0f / 25.0f;
    f32x4 r0, r1;
    r0[0] = (b0[0] + rd * lof(u3[0]) + dn * a0) * k;
    r0[1] = (b0[1] + rd * hif(u3[0]) + dn * a1) * k;
    r0[2] = (b0[2] + rd * lof(u3[1]) + dn * a2) * k;
    r0[3] = (b0[3] + rd * hif(u3[1]) + dn * a3) * k;
    r1[0] = (b1[0] + rd * lof(u3[2]) + dn * a4) * k;
    r1[1] = (b1[1] + rd * hif(u3[2]) + dn * a5) * k;
    r1[2] = (b1[2] + rd * lof(u3[3]) + dn * a6) * k;
    r1[3] = (b1[3] + rd * hif(u3[3]) + dn * a7) * k;
    __builtin_nontemporal_store(r0, (f32x4*)finP);
    __builtin_nontemporal_store(r1, (f32x4*)(finP + 4));
}

// ---------------- host ----------------

extern "C" void kernel_launch(void* const* d_in, const int* in_sizes, int n_in,
                              void* d_out, int out_size, void* d_ws, size_t ws_size,
                              hipStream_t stream) {
    const int*   edge = (const int*)d_in[0];
    const float* embU = (const float*)d_in[1];
    const float* embI = (const float*)d_in[2];
    const int E = in_sizes[0] / 2;
    const int* row = edge;
    const int* col = edge + E;

    float* out  = (float*)d_out;
    float* finU = out;
    float* cu   = out + (size_t)U_CNT * DIM;
    float* finI = out + (size_t)2 * U_CNT * DIM;
    float* ci   = finI + (size_t)I_CNT * DIM;

    // workspace carve-up
    const size_t XB = (size_t)N_CNT * DIM * sizeof(bf16_t);   // 64 MB
    char* ws = (char*)d_ws;
    size_t p = 0;
    bf16_t* w0 = (bf16_t*)(ws + p); p += XB;
    bf16_t* w1 = (bf16_t*)(ws + p); p += XB;
    bf16_t* w2 = (bf16_t*)(ws + p); p += XB;
    bf16_t* w3 = (bf16_t*)(ws + p); p += XB;
    bf16_t* s3 = (bf16_t*)(ws + p); p += XB;
    int*   cnt  = (int*)(ws + p);   p += ((size_t)N_CNT + 4) * sizeof(int);
    int*   off  = (int*)(ws + p);   p += ((size_t)N_CNT + 4) * sizeof(int);
    int*   cur  = (int*)(ws + p);   p += ((size_t)N_CNT + 4) * sizeof(int);
    float* dis  = (float*)(ws + p); p += ((size_t)N_CNT + 4) * sizeof(float);
    float* dis2 = (float*)(ws + p); p += ((size_t)N_CNT + 4) * sizeof(float);
    float* rdis = (float*)(ws + p); p += ((size_t)N_CNT + 4) * sizeof(float);
    int*   bsum = (int*)(ws + p);   p += 1024 * sizeof(int);
    int*   csr  = (int*)(ws + p);   p += (size_t)E * sizeof(int);               // 10 MB

    const float* embIadj = embI - (size_t)U_CNT * DIM;
    float* finIadj = finI - (size_t)U_CNT * DIM;
    float* ciadj   = ci   - (size_t)U_CNT * DIM;

    const int B = 256;
    const int gE  = (E + B - 1) / B;
    const int gW  = N_CNT * 16 / B;     // 31250 float4-blocks, exact
    const int gGather = N_CNT / 32;     // 15625, exact

    // 1. degree
    hipMemsetAsync(cnt, 0, (size_t)N_CNT * sizeof(int), stream);
    deg_cnt_kernel<<<gE, B, 0, stream>>>(col, cnt, E);

    // 2. scan + normalization arrays
    scan1_dis_kernel<<<NB1, 256, 0, stream>>>(cnt, bsum, dis, dis2, rdis, N_CNT);
    scan2_kernel<<<1, 512, 0, stream>>>(bsum, NB1);
    scan3_kernel<<<NB1, 256, 0, stream>>>(cnt, bsum, off, cur, N_CNT, E);

    // 3. bucketed fill (write window fits per-XCD L2 -> full-line merges), then w0 stream
    for (int k = 0; k < NPASS; k++)
        fill_bucket_kernel<<<gE, B, 0, stream>>>(row, col, cur, csr, E,
                                                 k * BUCKET, (k + 1) * BUCKET);
    w0_kernel<<<gW, B, 0, stream>>>(embU, embIadj, dis, (ushort4*)w0);

    // 4. layers 1..3 (+ distributed verbatim copies, + s3 in layer 3)
    gatherw_kernel<<<gGather, B, 0, stream>>>(off, csr, (const uint32_t*)w0, (uint4*)w1,
        dis2, E, nullptr, nullptr, nullptr, embU, cu, 0, U_CNT);
    gatherw_kernel<<<gGather, B, 0, stream>>>(off, csr, (const uint32_t*)w1, (uint4*)w2,
        dis2, E, nullptr, nullptr, nullptr, embIadj, ciadj, U_CNT, N_CNT);
    gatherw_kernel<<<gGather, B, 0, stream>>>(off, csr, (const uint32_t*)w2, (uint4*)w3,
        dis2, E, (u32x4*)s3, (const u32x4*)w1, (const u32x4*)w2, nullptr, nullptr, 0, 0);

    // 5. layer 4 + finalize
    final_kernel<<<gGather, B, 0, stream>>>(off, csr, (const uint32_t*)w3, (const u32x4*)s3,
        embU, embIadj, dis, rdis, finU, finIadj, E);
}

// Round 11
// 572.745 us; speedup vs baseline: 1.2845x; 1.0965x over previous
//
#include <hip/hip_runtime.h>
#include <stdint.h>

#define U_CNT 300000
#define I_CNT 200000
#define N_CNT 500000
#define DIM 64
#define SCAN_CHUNK 1024
#define NB1 ((N_CNT + SCAN_CHUNK - 1) / SCAN_CHUNK)   // 489
#define NPASS 4
#define BUCKET (N_CNT / NPASS)                        // 125000
#define F8SCALE 64.0f
#define F8INV   (1.0f / 64.0f)

typedef unsigned short bf16_t;
typedef float    f32x4 __attribute__((ext_vector_type(4)));
typedef float    f32x2 __attribute__((ext_vector_type(2)));
typedef uint32_t u32x4 __attribute__((ext_vector_type(4)));
typedef uint32_t u32x2 __attribute__((ext_vector_type(2)));

__device__ __forceinline__ float lof(uint32_t u) { return __uint_as_float(u << 16); }
__device__ __forceinline__ float hif(uint32_t u) { return __uint_as_float(u & 0xFFFF0000u); }
__device__ __forceinline__ uint32_t rnd_bf(float f) {
    uint32_t u = __float_as_uint(f);
    return u + (0x7FFFu + ((u >> 16) & 1u));
}
__device__ __forceinline__ uint32_t packbf(float lo, float hi) {
    return (rnd_bf(lo) >> 16) | (rnd_bf(hi) & 0xFFFF0000u);
}

// ---- fp8 e4m3 HW pack/unpack ----
__device__ __forceinline__ uint32_t enc4(float f0, float f1, float f2, float f3) {
    int v = 0;
    v = __builtin_amdgcn_cvt_pk_fp8_f32(f0, f1, v, false);
    v = __builtin_amdgcn_cvt_pk_fp8_f32(f2, f3, v, true);
    return (uint32_t)v;
}
__device__ __forceinline__ void dec8(u32x2 v, float* f) {
    f32x2 p0 = __builtin_amdgcn_cvt_pk_f32_fp8((int)v[0], false);
    f32x2 p1 = __builtin_amdgcn_cvt_pk_f32_fp8((int)v[0], true);
    f32x2 p2 = __builtin_amdgcn_cvt_pk_f32_fp8((int)v[1], false);
    f32x2 p3 = __builtin_amdgcn_cvt_pk_f32_fp8((int)v[1], true);
    f[0] = p0[0]; f[1] = p0[1]; f[2] = p1[0]; f[3] = p1[1];
    f[4] = p2[0]; f[5] = p2[1]; f[6] = p3[0]; f[7] = p3[1];
}
__device__ __forceinline__ void acc8(float nrm, u32x2 v, float* a) {
    float f[8];
    dec8(v, f);
    #pragma unroll
    for (int k = 0; k < 8; k++) a[k] = fmaf(nrm, f[k], a[k]);
}

// ---------------- degree ----------------

__global__ void deg_cnt_kernel(const int* __restrict__ col, int* __restrict__ cnt, int E) {
    int e = blockIdx.x * blockDim.x + threadIdx.x;
    if (e < E) atomicAdd(&cnt[col[e]], 1);
}

// ---------------- scan1 + normalization arrays ----------------

__global__ void scan1_dis_kernel(const int* __restrict__ cnt, int* __restrict__ bsum,
                                 float* __restrict__ dis, float* __restrict__ dis2,
                                 float* __restrict__ rdis, int n) {
    __shared__ int lds[256];
    int t = threadIdx.x;
    int i = blockIdx.x * SCAN_CHUNK + t * 4;
    int4 v = make_int4(0, 0, 0, 0);
    if (i + 3 < n) v = *(const int4*)(cnt + i);
    else {
        if (i     < n) v.x = cnt[i];
        if (i + 1 < n) v.y = cnt[i + 1];
        if (i + 2 < n) v.z = cnt[i + 2];
        if (i + 3 < n) v.w = cnt[i + 3];
    }
    if (i + 3 < n) {
        int dd[4] = {v.x, v.y, v.z, v.w};
        f32x4 fd, f2, fr;
        #pragma unroll
        for (int k = 0; k < 4; k++) {
            float d = (float)dd[k];
            float s = dd[k] > 0 ? rsqrtf(d) : 0.0f;
            fd[k] = s; f2[k] = s * s; fr[k] = d * s;
        }
        *(f32x4*)(dis + i) = fd;
        *(f32x4*)(dis2 + i) = f2;
        *(f32x4*)(rdis + i) = fr;
    } else {
        for (int k = 0; k < 4 && i + k < n; k++) {
            int d = (&v.x)[k];
            float s = d > 0 ? rsqrtf((float)d) : 0.0f;
            dis[i + k] = s; dis2[i + k] = s * s; rdis[i + k] = (float)d * s;
        }
    }
    lds[t] = v.x + v.y + v.z + v.w;
    __syncthreads();
    for (int o = 128; o > 0; o >>= 1) {
        if (t < o) lds[t] += lds[t + o];
        __syncthreads();
    }
    if (t == 0) bsum[blockIdx.x] = lds[0];
}

__global__ void scan2_kernel(int* __restrict__ bsum, int nb) {
    __shared__ int lds[512];
    int t = threadIdx.x;
    int v = (t < nb) ? bsum[t] : 0;
    lds[t] = v;
    __syncthreads();
    for (int o = 1; o < 512; o <<= 1) {
        int a = lds[t] + ((t >= o) ? lds[t - o] : 0);
        __syncthreads();
        lds[t] = a;
        __syncthreads();
    }
    if (t < nb) bsum[t] = lds[t] - v;
}

__global__ void scan3_kernel(const int* __restrict__ cnt, const int* __restrict__ bsum,
                             int* __restrict__ off, int* __restrict__ cur, int n, int E) {
    __shared__ int lds[256];
    int t = threadIdx.x;
    int i = blockIdx.x * SCAN_CHUNK + t * 4;
    int4 v = make_int4(0, 0, 0, 0);
    if (i + 3 < n) v = *(const int4*)(cnt + i);
    else {
        if (i     < n) v.x = cnt[i];
        if (i + 1 < n) v.y = cnt[i + 1];
        if (i + 2 < n) v.z = cnt[i + 2];
        if (i + 3 < n) v.w = cnt[i + 3];
    }
    int s = v.x + v.y + v.z + v.w;
    lds[t] = s;
    __syncthreads();
    for (int o = 1; o < 256; o <<= 1) {
        int a = lds[t] + ((t >= o) ? lds[t - o] : 0);
        __syncthreads();
        lds[t] = a;
        __syncthreads();
    }
    int ex = lds[t] - s + bsum[blockIdx.x];
    int o0 = ex, o1 = ex + v.x, o2 = o1 + v.y, o3 = o2 + v.z;
    if (i     < n) { off[i]     = o0; cur[i]     = o0; }
    if (i + 1 < n) { off[i + 1] = o1; cur[i + 1] = o1; }
    if (i + 2 < n) { off[i + 2] = o2; cur[i + 2] = o2; }
    if (i + 3 < n) { off[i + 3] = o3; cur[i + 3] = o3; }
    if (i == n - 4) off[n] = E;   // N_CNT % 4 == 0
}

// ---------------- bucketed fill ----------------

__global__ void fill_bucket_kernel(const int* __restrict__ row, const int* __restrict__ col,
                                   int* __restrict__ cur, int* __restrict__ csr, int E,
                                   int lo, int hi) {
    int e = blockIdx.x * blockDim.x + threadIdx.x;
    if (e < E) {
        int c = col[e];
        if (c >= lo && c < hi) {
            int p = atomicAdd(&cur[c], 1);
            csr[p] = row[e];
        }
    }
}

// ---------------- w0 = fp8(64*dis*x0) + verbatim copy (both read emb once) ----------------

__global__ void w0copy_kernel(const float* __restrict__ embU, const float* __restrict__ embIadj,
                              const float* __restrict__ dis, uint32_t* __restrict__ w0,
                              float* __restrict__ cpyU, float* __restrict__ cpyIadj) {
    int q = blockIdx.x * blockDim.x + threadIdx.x;   // float4 index over N_CNT*16
    int node = q >> 4;
    const float* src = (node < U_CNT ? embU : embIadj);
    float*       dst = (node < U_CNT ? cpyU : cpyIadj);
    f32x4 v = *((const f32x4*)src + q);
    float dn = dis[node] * F8SCALE;
    w0[q] = enc4(v[0] * dn, v[1] * dn, v[2] * dn, v[3] * dn);
    __builtin_nontemporal_store(v, (f32x4*)dst + q);
}

// ---------------- fp8 gather (layers 1..3) ----------------
// w_out[c] = fp8( dis2[c] * sum_r w_in[r] )   (scale cancels in recursion)
// layer 3 also emits s3 = (w1 + w2 + w3)/64 in bf16
__global__ __launch_bounds__(256) void gatherf8_kernel(
        const int* __restrict__ off, const int* __restrict__ csr,
        const u32x2* __restrict__ w_in, u32x2* __restrict__ w_out,
        const float* __restrict__ dis2, int nE,
        u32x4* __restrict__ s_out, const u32x2* __restrict__ w1, const u32x2* __restrict__ w2) {
    int lane = threadIdx.x & 63;
    int sub  = lane & 7;
    int n = blockIdx.x * 32 + (threadIdx.x >> 6) * 8 + (lane >> 3);  // N_CNT % 32 == 0
    int s = off[n], e = off[n + 1];
    size_t nodeOff = ((size_t)n << 3) + sub;

    u32x2 u1v = {0, 0}, u2v = {0, 0};
    if (s_out) {
        u1v = __builtin_nontemporal_load(w1 + nodeOff);
        u2v = __builtin_nontemporal_load(w2 + nodeOff);
    }

    float a[8] = {0, 0, 0, 0, 0, 0, 0, 0};

    int i0 = s;
    int ca = csr[(i0     < nE) ? i0     : (nE - 1)];
    int cb = csr[(i0 + 1 < nE) ? i0 + 1 : (nE - 1)];
    float na = (i0     < e) ? 1.0f : 0.0f;
    float nb = (i0 + 1 < e) ? 1.0f : 0.0f;
    int   ra = (i0     < e) ? ca : 0;
    int   rb = (i0 + 1 < e) ? cb : 0;
    u32x2 va = w_in[((size_t)ra << 3) + sub];
    u32x2 vb = w_in[((size_t)rb << 3) + sub];
    int i1 = i0 + 2;
    int qa = csr[(i1     < nE) ? i1     : (nE - 1)];
    int qb = csr[(i1 + 1 < nE) ? i1 + 1 : (nE - 1)];

    while (i0 < e) {
        float ma = (i1     < e) ? 1.0f : 0.0f;
        float mb = (i1 + 1 < e) ? 1.0f : 0.0f;
        int   sa = (i1     < e) ? qa : 0;
        int   sb = (i1 + 1 < e) ? qb : 0;
        u32x2 wa = w_in[((size_t)sa << 3) + sub];
        u32x2 wb = w_in[((size_t)sb << 3) + sub];
        int i2 = i1 + 2;
        qa = csr[(i2     < nE) ? i2     : (nE - 1)];
        qb = csr[(i2 + 1 < nE) ? i2 + 1 : (nE - 1)];
        acc8(na, va, a);
        acc8(nb, vb, a);
        va = wa; vb = wb; na = ma; nb = mb;
        i0 = i1; i1 = i2;
    }

    float d2 = dis2[n];
    u32x2 wv;
    wv[0] = enc4(d2 * a[0], d2 * a[1], d2 * a[2], d2 * a[3]);
    wv[1] = enc4(d2 * a[4], d2 * a[5], d2 * a[6], d2 * a[7]);
    w_out[nodeOff] = wv;   // cached: next layer's gather source

    if (s_out) {
        float f1[8], f2v[8];
        dec8(u1v, f1);
        dec8(u2v, f2v);
        float sv[8];
        #pragma unroll
        for (int k = 0; k < 8; k++) sv[k] = (f1[k] + f2v[k] + d2 * a[k]) * F8INV;
        u32x4 sb;
        sb[0] = packbf(sv[0], sv[1]); sb[1] = packbf(sv[2], sv[3]);
        sb[2] = packbf(sv[4], sv[5]); sb[3] = packbf(sv[6], sv[7]);
        __builtin_nontemporal_store(sb, s_out + nodeOff);
    }
}

// ---------------- final: fp8 gather layer 4 + finalize ----------------
// fin = (emb + rdis*s3 + dis*(a/64)) / 25

__global__ __launch_bounds__(256) void finalf8_kernel(
        const int* __restrict__ off, const int* __restrict__ csr,
        const u32x2* __restrict__ w3, const u32x4* __restrict__ s3,
        const float* __restrict__ embU, const float* __restrict__ embIadj,
        const float* __restrict__ dis, const float* __restrict__ rdis,
        float* __restrict__ finU, float* __restrict__ finIadj, int nE) {
    int lane = threadIdx.x & 63;
    int sub  = lane & 7;
    int n = blockIdx.x * 32 + (threadIdx.x >> 6) * 8 + (lane >> 3);
    int s = off[n], e = off[n + 1];
    size_t nodeOff = ((size_t)n << 3) + sub;
    size_t fbase   = ((size_t)n << 6) + (size_t)sub * 8;

    const float* embP = (n < U_CNT ? embU : embIadj) + fbase;
    float*       finP = (n < U_CNT ? finU : finIadj) + fbase;
    f32x4 b0 = __builtin_nontemporal_load((const f32x4*)embP);
    f32x4 b1 = __builtin_nontemporal_load((const f32x4*)(embP + 4));
    u32x4 u3 = __builtin_nontemporal_load(s3 + nodeOff);

    float a[8] = {0, 0, 0, 0, 0, 0, 0, 0};

    int i0 = s;
    int ca = csr[(i0     < nE) ? i0     : (nE - 1)];
    int cb = csr[(i0 + 1 < nE) ? i0 + 1 : (nE - 1)];
    float na = (i0     < e) ? 1.0f : 0.0f;
    float nb = (i0 + 1 < e) ? 1.0f : 0.0f;
    int   ra = (i0     < e) ? ca : 0;
    int   rb = (i0 + 1 < e) ? cb : 0;
    u32x2 va = w3[((size_t)ra << 3) + sub];
    u32x2 vb = w3[((size_t)rb << 3) + sub];
    int i1 = i0 + 2;
    int qa = csr[(i1     < nE) ? i1     : (nE - 1)];
    int qb = csr[(i1 + 1 < nE) ? i1 + 1 : (nE - 1)];

    while (i0 < e) {
        float ma = (i1     < e) ? 1.0f : 0.0f;
        float mb = (i1 + 1 < e) ? 1.0f : 0.0f;
        int   sa = (i1     < e) ? qa : 0;
        int   sb = (i1 + 1 < e) ? qb : 0;
        u32x2 wa = w3[((size_t)sa << 3) + sub];
        u32x2 wb = w3[((size_t)sb << 3) + sub];
        int i2 = i1 + 2;
        qa = csr[(i2     < nE) ? i2     : (nE - 1)];
        qb = csr[(i2 + 1 < nE) ? i2 + 1 : (nE - 1)];
        acc8(na, va, a);
        acc8(nb, vb, a);
        va = wa; vb = wb; na = ma; nb = mb;
        i0 = i1; i1 = i2;
    }

    float dn = dis[n] * F8INV;
    float rd = rdis[n];
    const float k = 1.0f / 25.0f;
    f32x4 r0, r1;
    r0[0] = (b0[0] + rd * lof(u3[0]) + dn * a[0]) * k;
    r0[1] = (b0[1] + rd * hif(u3[0]) + dn * a[1]) * k;
    r0[2] = (b0[2] + rd * lof(u3[1]) + dn * a[2]) * k;
    r0[3] = (b0[3] + rd * hif(u3[1]) + dn * a[3]) * k;
    r1[0] = (b1[0] + rd * lof(u3[2]) + dn * a[4]) * k;
    r1[1] = (b1[1] + rd * hif(u3[2]) + dn * a[5]) * k;
    r1[2] = (b1[2] + rd * lof(u3[3]) + dn * a[6]) * k;
    r1[3] = (b1[3] + rd * hif(u3[3]) + dn * a[7]) * k;
    __builtin_nontemporal_store(r0, (f32x4*)finP);
    __builtin_nontemporal_store(r1, (f32x4*)(finP + 4));
}

// ---------------- host ----------------

extern "C" void kernel_launch(void* const* d_in, const int* in_sizes, int n_in,
                              void* d_out, int out_size, void* d_ws, size_t ws_size,
                              hipStream_t stream) {
    const int*   edge = (const int*)d_in[0];
    const float* embU = (const float*)d_in[1];
    const float* embI = (const float*)d_in[2];
    const int E = in_sizes[0] / 2;
    const int* row = edge;
    const int* col = edge + E;

    float* out  = (float*)d_out;
    float* finU = out;
    float* cu   = out + (size_t)U_CNT * DIM;
    float* finI = out + (size_t)2 * U_CNT * DIM;
    float* ci   = finI + (size_t)I_CNT * DIM;

    // workspace carve-up
    const size_t W8 = (size_t)N_CNT * DIM;            // 32 MB (1 B per elem)
    const size_t SB = (size_t)N_CNT * DIM * 2;        // 64 MB (bf16)
    char* ws = (char*)d_ws;
    size_t p = 0;
    uint32_t* w0 = (uint32_t*)(ws + p); p += W8;
    uint32_t* w1 = (uint32_t*)(ws + p); p += W8;
    uint32_t* w2 = (uint32_t*)(ws + p); p += W8;
    uint32_t* w3 = (uint32_t*)(ws + p); p += W8;
    bf16_t*   s3 = (bf16_t*)(ws + p);   p += SB;
    int*   cnt  = (int*)(ws + p);   p += ((size_t)N_CNT + 4) * sizeof(int);
    int*   off  = (int*)(ws + p);   p += ((size_t)N_CNT + 4) * sizeof(int);
    int*   cur  = (int*)(ws + p);   p += ((size_t)N_CNT + 4) * sizeof(int);
    float* dis  = (float*)(ws + p); p += ((size_t)N_CNT + 4) * sizeof(float);
    float* dis2 = (float*)(ws + p); p += ((size_t)N_CNT + 4) * sizeof(float);
    float* rdis = (float*)(ws + p); p += ((size_t)N_CNT + 4) * sizeof(float);
    int*   bsum = (int*)(ws + p);   p += 1024 * sizeof(int);
    int*   csr  = (int*)(ws + p);   p += (size_t)E * sizeof(int);               // 10 MB

    const float* embIadj = embI - (size_t)U_CNT * DIM;
    float* finIadj = finI - (size_t)U_CNT * DIM;
    float* ciadj   = ci   - (size_t)U_CNT * DIM;

    const int B = 256;
    const int gE  = (E + B - 1) / B;
    const int gW  = N_CNT * 16 / B;     // 31250, exact
    const int gGather = N_CNT / 32;     // 15625, exact

    // 1. degree
    hipMemsetAsync(cnt, 0, (size_t)N_CNT * sizeof(int), stream);
    deg_cnt_kernel<<<gE, B, 0, stream>>>(col, cnt, E);

    // 2. scan + normalization arrays
    scan1_dis_kernel<<<NB1, 256, 0, stream>>>(cnt, bsum, dis, dis2, rdis, N_CNT);
    scan2_kernel<<<1, 512, 0, stream>>>(bsum, NB1);
    scan3_kernel<<<NB1, 256, 0, stream>>>(cnt, bsum, off, cur, N_CNT, E);

    // 3. bucketed fill
    for (int k = 0; k < NPASS; k++)
        fill_bucket_kernel<<<gE, B, 0, stream>>>(row, col, cur, csr, E,
                                                 k * BUCKET, (k + 1) * BUCKET);

    // 4. w0 (fp8) + verbatim copies, single emb read
    w0copy_kernel<<<gW, B, 0, stream>>>(embU, embIadj, dis, w0, cu, ciadj);

    // 5. layers 1..3 (fp8 gathers; layer 3 emits s3)
    gatherf8_kernel<<<gGather, B, 0, stream>>>(off, csr, (const u32x2*)w0, (u32x2*)w1,
        dis2, E, nullptr, nullptr, nullptr);
    gatherf8_kernel<<<gGather, B, 0, stream>>>(off, csr, (const u32x2*)w1, (u32x2*)w2,
        dis2, E, nullptr, nullptr, nullptr);
    gatherf8_kernel<<<gGather, B, 0, stream>>>(off, csr, (const u32x2*)w2, (u32x2*)w3,
        dis2, E, (u32x4*)s3, (const u32x2*)w1, (const u32x2*)w2);

    // 6. layer 4 + finalize
    finalf8_kernel<<<gGather, B, 0, stream>>>(off, csr, (const u32x2*)w3, (const u32x4*)s3,
        embU, embIadj, dis, rdis, finU, finIadj, E);
}

// Round 12
// 557.263 us; speedup vs baseline: 1.3202x; 1.0278x over previous
//
#include <hip/hip_runtime.h>
#include <stdint.h>

#define U_CNT 300000
#define I_CNT 200000
#define N_CNT 500000
#define DIM 64
#define SCAN_CHUNK 1024
#define NB1 ((N_CNT + SCAN_CHUNK - 1) / SCAN_CHUNK)   // 489
#define NPASS 4
#define BUCKET (N_CNT / NPASS)                        // 125000
#define F8SCALE 64.0f
#define F8INV   (1.0f / 64.0f)

typedef unsigned short bf16_t;
typedef float    f32x4 __attribute__((ext_vector_type(4)));
typedef float    f32x2 __attribute__((ext_vector_type(2)));
typedef uint32_t u32x4 __attribute__((ext_vector_type(4)));
typedef uint32_t u32x2 __attribute__((ext_vector_type(2)));

__device__ __forceinline__ float lof(uint32_t u) { return __uint_as_float(u << 16); }
__device__ __forceinline__ float hif(uint32_t u) { return __uint_as_float(u & 0xFFFF0000u); }
__device__ __forceinline__ uint32_t rnd_bf(float f) {
    uint32_t u = __float_as_uint(f);
    return u + (0x7FFFu + ((u >> 16) & 1u));
}
__device__ __forceinline__ uint32_t packbf(float lo, float hi) {
    return (rnd_bf(lo) >> 16) | (rnd_bf(hi) & 0xFFFF0000u);
}

// ---- fp8 e4m3 HW pack/unpack ----
__device__ __forceinline__ uint32_t enc4(float f0, float f1, float f2, float f3) {
    int v = 0;
    v = __builtin_amdgcn_cvt_pk_fp8_f32(f0, f1, v, false);
    v = __builtin_amdgcn_cvt_pk_fp8_f32(f2, f3, v, true);
    return (uint32_t)v;
}
__device__ __forceinline__ void dec8(u32x2 v, float* f) {
    f32x2 p0 = __builtin_amdgcn_cvt_pk_f32_fp8((int)v[0], false);
    f32x2 p1 = __builtin_amdgcn_cvt_pk_f32_fp8((int)v[0], true);
    f32x2 p2 = __builtin_amdgcn_cvt_pk_f32_fp8((int)v[1], false);
    f32x2 p3 = __builtin_amdgcn_cvt_pk_f32_fp8((int)v[1], true);
    f[0] = p0[0]; f[1] = p0[1]; f[2] = p1[0]; f[3] = p1[1];
    f[4] = p2[0]; f[5] = p2[1]; f[6] = p3[0]; f[7] = p3[1];
}
__device__ __forceinline__ void acc8(float nrm, u32x2 v, float* a) {
    float f[8];
    dec8(v, f);
    #pragma unroll
    for (int k = 0; k < 8; k++) a[k] = fmaf(nrm, f[k], a[k]);
}

// ---------------- degree ----------------

__global__ void deg_cnt_kernel(const int* __restrict__ col, int* __restrict__ cnt, int E) {
    int e = blockIdx.x * blockDim.x + threadIdx.x;
    if (e < E) atomicAdd(&cnt[col[e]], 1);
}

// ---------------- scan1 + normalization arrays ----------------

__global__ void scan1_dis_kernel(const int* __restrict__ cnt, int* __restrict__ bsum,
                                 float* __restrict__ dis, float* __restrict__ dis2,
                                 float* __restrict__ rdis, int n) {
    __shared__ int lds[256];
    int t = threadIdx.x;
    int i = blockIdx.x * SCAN_CHUNK + t * 4;
    int4 v = make_int4(0, 0, 0, 0);
    if (i + 3 < n) v = *(const int4*)(cnt + i);
    else {
        if (i     < n) v.x = cnt[i];
        if (i + 1 < n) v.y = cnt[i + 1];
        if (i + 2 < n) v.z = cnt[i + 2];
        if (i + 3 < n) v.w = cnt[i + 3];
    }
    if (i + 3 < n) {
        int dd[4] = {v.x, v.y, v.z, v.w};
        f32x4 fd, f2, fr;
        #pragma unroll
        for (int k = 0; k < 4; k++) {
            float d = (float)dd[k];
            float s = dd[k] > 0 ? rsqrtf(d) : 0.0f;
            fd[k] = s; f2[k] = s * s; fr[k] = d * s;
        }
        *(f32x4*)(dis + i) = fd;
        *(f32x4*)(dis2 + i) = f2;
        *(f32x4*)(rdis + i) = fr;
    } else {
        for (int k = 0; k < 4 && i + k < n; k++) {
            int d = (&v.x)[k];
            float s = d > 0 ? rsqrtf((float)d) : 0.0f;
            dis[i + k] = s; dis2[i + k] = s * s; rdis[i + k] = (float)d * s;
        }
    }
    lds[t] = v.x + v.y + v.z + v.w;
    __syncthreads();
    for (int o = 128; o > 0; o >>= 1) {
        if (t < o) lds[t] += lds[t + o];
        __syncthreads();
    }
    if (t == 0) bsum[blockIdx.x] = lds[0];
}

__global__ void scan2_kernel(int* __restrict__ bsum, int nb) {
    __shared__ int lds[512];
    int t = threadIdx.x;
    int v = (t < nb) ? bsum[t] : 0;
    lds[t] = v;
    __syncthreads();
    for (int o = 1; o < 512; o <<= 1) {
        int a = lds[t] + ((t >= o) ? lds[t - o] : 0);
        __syncthreads();
        lds[t] = a;
        __syncthreads();
    }
    if (t < nb) bsum[t] = lds[t] - v;
}

__global__ void scan3_kernel(const int* __restrict__ cnt, const int* __restrict__ bsum,
                             int* __restrict__ off, int* __restrict__ cur, int n, int E) {
    __shared__ int lds[256];
    int t = threadIdx.x;
    int i = blockIdx.x * SCAN_CHUNK + t * 4;
    int4 v = make_int4(0, 0, 0, 0);
    if (i + 3 < n) v = *(const int4*)(cnt + i);
    else {
        if (i     < n) v.x = cnt[i];
        if (i + 1 < n) v.y = cnt[i + 1];
        if (i + 2 < n) v.z = cnt[i + 2];
        if (i + 3 < n) v.w = cnt[i + 3];
    }
    int s = v.x + v.y + v.z + v.w;
    lds[t] = s;
    __syncthreads();
    for (int o = 1; o < 256; o <<= 1) {
        int a = lds[t] + ((t >= o) ? lds[t - o] : 0);
        __syncthreads();
        lds[t] = a;
        __syncthreads();
    }
    int ex = lds[t] - s + bsum[blockIdx.x];
    int o0 = ex, o1 = ex + v.x, o2 = o1 + v.y, o3 = o2 + v.z;
    if (i     < n) { off[i]     = o0; cur[i]     = o0; }
    if (i + 1 < n) { off[i + 1] = o1; cur[i + 1] = o1; }
    if (i + 2 < n) { off[i + 2] = o2; cur[i + 2] = o2; }
    if (i + 3 < n) { off[i + 3] = o3; cur[i + 3] = o3; }
    if (i == n - 4) off[n] = E;   // N_CNT % 4 == 0
}

// ---------------- bucketed fill ----------------

__global__ void fill_bucket_kernel(const int* __restrict__ row, const int* __restrict__ col,
                                   int* __restrict__ cur, int* __restrict__ csr, int E,
                                   int lo, int hi) {
    int e = blockIdx.x * blockDim.x + threadIdx.x;
    if (e < E) {
        int c = col[e];
        if (c >= lo && c < hi) {
            int p = atomicAdd(&cur[c], 1);
            csr[p] = row[e];
        }
    }
}

// ---------------- w0 = fp8(64*dis*x0) + verbatim f32 copy + bf16 emb (e16) ----------------

__global__ void w0copy_kernel(const float* __restrict__ embU, const float* __restrict__ embIadj,
                              const float* __restrict__ dis, uint32_t* __restrict__ w0,
                              float* __restrict__ cpyU, float* __restrict__ cpyIadj,
                              u32x2* __restrict__ e16) {
    int q = blockIdx.x * blockDim.x + threadIdx.x;   // float4 index over N_CNT*16
    int node = q >> 4;
    const float* src = (node < U_CNT ? embU : embIadj);
    float*       dst = (node < U_CNT ? cpyU : cpyIadj);
    f32x4 v = *((const f32x4*)src + q);
    float dn = dis[node] * F8SCALE;
    w0[q] = enc4(v[0] * dn, v[1] * dn, v[2] * dn, v[3] * dn);
    u32x2 eb;
    eb[0] = packbf(v[0], v[1]);
    eb[1] = packbf(v[2], v[3]);
    __builtin_nontemporal_store(eb, e16 + q);
    __builtin_nontemporal_store(v, (f32x4*)dst + q);
}

// ---------------- fp8 gather (layers 1..3, pure) ----------------
// w_out[c] = fp8( dis2[c] * sum_r w_in[r] )

__global__ __launch_bounds__(256) void gatherf8_kernel(
        const int* __restrict__ off, const int* __restrict__ csr,
        const u32x2* __restrict__ w_in, u32x2* __restrict__ w_out,
        const float* __restrict__ dis2, int nE) {
    int lane = threadIdx.x & 63;
    int sub  = lane & 7;
    int n = blockIdx.x * 32 + (threadIdx.x >> 6) * 8 + (lane >> 3);  // N_CNT % 32 == 0
    int s = off[n], e = off[n + 1];
    size_t nodeOff = ((size_t)n << 3) + sub;

    float a[8] = {0, 0, 0, 0, 0, 0, 0, 0};

    int i0 = s;
    int ca = csr[(i0     < nE) ? i0     : (nE - 1)];
    int cb = csr[(i0 + 1 < nE) ? i0 + 1 : (nE - 1)];
    float na = (i0     < e) ? 1.0f : 0.0f;
    float nb = (i0 + 1 < e) ? 1.0f : 0.0f;
    int   ra = (i0     < e) ? ca : 0;
    int   rb = (i0 + 1 < e) ? cb : 0;
    u32x2 va = w_in[((size_t)ra << 3) + sub];
    u32x2 vb = w_in[((size_t)rb << 3) + sub];
    int i1 = i0 + 2;
    int qa = csr[(i1     < nE) ? i1     : (nE - 1)];
    int qb = csr[(i1 + 1 < nE) ? i1 + 1 : (nE - 1)];

    while (i0 < e) {
        float ma = (i1     < e) ? 1.0f : 0.0f;
        float mb = (i1 + 1 < e) ? 1.0f : 0.0f;
        int   sa = (i1     < e) ? qa : 0;
        int   sb = (i1 + 1 < e) ? qb : 0;
        u32x2 wa = w_in[((size_t)sa << 3) + sub];
        u32x2 wb = w_in[((size_t)sb << 3) + sub];
        int i2 = i1 + 2;
        qa = csr[(i2     < nE) ? i2     : (nE - 1)];
        qb = csr[(i2 + 1 < nE) ? i2 + 1 : (nE - 1)];
        acc8(na, va, a);
        acc8(nb, vb, a);
        va = wa; vb = wb; na = ma; nb = mb;
        i0 = i1; i1 = i2;
    }

    float d2 = dis2[n];
    u32x2 wv;
    wv[0] = enc4(d2 * a[0], d2 * a[1], d2 * a[2], d2 * a[3]);
    wv[1] = enc4(d2 * a[4], d2 * a[5], d2 * a[6], d2 * a[7]);
    w_out[nodeOff] = wv;
}

// ---------------- final: fp8 gather layer 4 + finalize ----------------
// fin = (e16 + rdis/64*(W1+W2+W3) + dis/64*a) / 25

__global__ __launch_bounds__(256) void finalf8_kernel(
        const int* __restrict__ off, const int* __restrict__ csr,
        const u32x2* __restrict__ w1, const u32x2* __restrict__ w2,
        const u32x2* __restrict__ w3, const u32x2* __restrict__ e16,
        const float* __restrict__ dis, const float* __restrict__ rdis,
        float* __restrict__ finU, float* __restrict__ finIadj, int nE) {
    int lane = threadIdx.x & 63;
    int sub  = lane & 7;
    int n = blockIdx.x * 32 + (threadIdx.x >> 6) * 8 + (lane >> 3);
    int s = off[n], e = off[n + 1];
    size_t nodeOff = ((size_t)n << 3) + sub;
    size_t fbase   = ((size_t)n << 6) + (size_t)sub * 8;

    float*       finP = (n < U_CNT ? finU : finIadj) + fbase;
    // independent streaming loads, issued before the gather loop
    u32x2 eb0 = __builtin_nontemporal_load(e16 + nodeOff * 2);
    u32x2 eb1 = __builtin_nontemporal_load(e16 + nodeOff * 2 + 1);
    u32x2 u1v = __builtin_nontemporal_load(w1 + nodeOff);
    u32x2 u2v = __builtin_nontemporal_load(w2 + nodeOff);
    u32x2 u3v = __builtin_nontemporal_load(w3 + nodeOff);

    float a[8] = {0, 0, 0, 0, 0, 0, 0, 0};

    int i0 = s;
    int ca = csr[(i0     < nE) ? i0     : (nE - 1)];
    int cb = csr[(i0 + 1 < nE) ? i0 + 1 : (nE - 1)];
    float na = (i0     < e) ? 1.0f : 0.0f;
    float nb = (i0 + 1 < e) ? 1.0f : 0.0f;
    int   ra = (i0     < e) ? ca : 0;
    int   rb = (i0 + 1 < e) ? cb : 0;
    u32x2 va = w3[((size_t)ra << 3) + sub];
    u32x2 vb = w3[((size_t)rb << 3) + sub];
    int i1 = i0 + 2;
    int qa = csr[(i1     < nE) ? i1     : (nE - 1)];
    int qb = csr[(i1 + 1 < nE) ? i1 + 1 : (nE - 1)];

    while (i0 < e) {
        float ma = (i1     < e) ? 1.0f : 0.0f;
        float mb = (i1 + 1 < e) ? 1.0f : 0.0f;
        int   sa = (i1     < e) ? qa : 0;
        int   sb = (i1 + 1 < e) ? qb : 0;
        u32x2 wa = w3[((size_t)sa << 3) + sub];
        u32x2 wb = w3[((size_t)sb << 3) + sub];
        int i2 = i1 + 2;
        qa = csr[(i2     < nE) ? i2     : (nE - 1)];
        qb = csr[(i2 + 1 < nE) ? i2 + 1 : (nE - 1)];
        acc8(na, va, a);
        acc8(nb, vb, a);
        va = wa; vb = wb; na = ma; nb = mb;
        i0 = i1; i1 = i2;
    }

    float f1[8], f2v[8], f3[8];
    dec8(u1v, f1);
    dec8(u2v, f2v);
    dec8(u3v, f3);

    float dn = dis[n] * F8INV;
    float rd = rdis[n] * F8INV;
    const float k = 1.0f / 25.0f;
    float eb[8] = { lof(eb0[0]), hif(eb0[0]), lof(eb0[1]), hif(eb0[1]),
                    lof(eb1[0]), hif(eb1[0]), lof(eb1[1]), hif(eb1[1]) };
    f32x4 r0, r1;
    r0[0] = (eb[0] + rd * (f1[0] + f2v[0] + f3[0]) + dn * a[0]) * k;
    r0[1] = (eb[1] + rd * (f1[1] + f2v[1] + f3[1]) + dn * a[1]) * k;
    r0[2] = (eb[2] + rd * (f1[2] + f2v[2] + f3[2]) + dn * a[2]) * k;
    r0[3] = (eb[3] + rd * (f1[3] + f2v[3] + f3[3]) + dn * a[3]) * k;
    r1[0] = (eb[4] + rd * (f1[4] + f2v[4] + f3[4]) + dn * a[4]) * k;
    r1[1] = (eb[5] + rd * (f1[5] + f2v[5] + f3[5]) + dn * a[5]) * k;
    r1[2] = (eb[6] + rd * (f1[6] + f2v[6] + f3[6]) + dn * a[6]) * k;
    r1[3] = (eb[7] + rd * (f1[7] + f2v[7] + f3[7]) + dn * a[7]) * k;
    __builtin_nontemporal_store(r0, (f32x4*)finP);
    __builtin_nontemporal_store(r1, (f32x4*)(finP + 4));
}

// ---------------- host ----------------

extern "C" void kernel_launch(void* const* d_in, const int* in_sizes, int n_in,
                              void* d_out, int out_size, void* d_ws, size_t ws_size,
                              hipStream_t stream) {
    const int*   edge = (const int*)d_in[0];
    const float* embU = (const float*)d_in[1];
    const float* embI = (const float*)d_in[2];
    const int E = in_sizes[0] / 2;
    const int* row = edge;
    const int* col = edge + E;

    float* out  = (float*)d_out;
    float* finU = out;
    float* cu   = out + (size_t)U_CNT * DIM;
    float* finI = out + (size_t)2 * U_CNT * DIM;
    float* ci   = finI + (size_t)I_CNT * DIM;

    // workspace carve-up
    const size_t W8 = (size_t)N_CNT * DIM;            // 32 MB (1 B per elem)
    const size_t SB = (size_t)N_CNT * DIM * 2;        // 64 MB (bf16)
    char* ws = (char*)d_ws;
    size_t p = 0;
    uint32_t* w0 = (uint32_t*)(ws + p); p += W8;
    uint32_t* w1 = (uint32_t*)(ws + p); p += W8;
    uint32_t* w2 = (uint32_t*)(ws + p); p += W8;
    uint32_t* w3 = (uint32_t*)(ws + p); p += W8;
    bf16_t*   e16 = (bf16_t*)(ws + p);  p += SB;
    int*   cnt  = (int*)(ws + p);   p += ((size_t)N_CNT + 4) * sizeof(int);
    int*   off  = (int*)(ws + p);   p += ((size_t)N_CNT + 4) * sizeof(int);
    int*   cur  = (int*)(ws + p);   p += ((size_t)N_CNT + 4) * sizeof(int);
    float* dis  = (float*)(ws + p); p += ((size_t)N_CNT + 4) * sizeof(float);
    float* dis2 = (float*)(ws + p); p += ((size_t)N_CNT + 4) * sizeof(float);
    float* rdis = (float*)(ws + p); p += ((size_t)N_CNT + 4) * sizeof(float);
    int*   bsum = (int*)(ws + p);   p += 1024 * sizeof(int);
    int*   csr  = (int*)(ws + p);   p += (size_t)E * sizeof(int);               // 10 MB

    const float* embIadj = embI - (size_t)U_CNT * DIM;
    float* finIadj = finI - (size_t)U_CNT * DIM;
    float* ciadj   = ci   - (size_t)U_CNT * DIM;

    const int B = 256;
    const int gE  = (E + B - 1) / B;
    const int gW  = N_CNT * 16 / B;     // 31250, exact
    const int gGather = N_CNT / 32;     // 15625, exact

    // 1. degree
    hipMemsetAsync(cnt, 0, (size_t)N_CNT * sizeof(int), stream);
    deg_cnt_kernel<<<gE, B, 0, stream>>>(col, cnt, E);

    // 2. scan + normalization arrays
    scan1_dis_kernel<<<NB1, 256, 0, stream>>>(cnt, bsum, dis, dis2, rdis, N_CNT);
    scan2_kernel<<<1, 512, 0, stream>>>(bsum, NB1);
    scan3_kernel<<<NB1, 256, 0, stream>>>(cnt, bsum, off, cur, N_CNT, E);

    // 3. bucketed fill
    for (int k = 0; k < NPASS; k++)
        fill_bucket_kernel<<<gE, B, 0, stream>>>(row, col, cur, csr, E,
                                                 k * BUCKET, (k + 1) * BUCKET);

    // 4. w0 (fp8) + verbatim copies + bf16 emb, single emb read
    w0copy_kernel<<<gW, B, 0, stream>>>(embU, embIadj, dis, w0, cu, ciadj, (u32x2*)e16);

    // 5. layers 1..3 (pure fp8 gathers)
    gatherf8_kernel<<<gGather, B, 0, stream>>>(off, csr, (const u32x2*)w0, (u32x2*)w1, dis2, E);
    gatherf8_kernel<<<gGather, B, 0, stream>>>(off, csr, (const u32x2*)w1, (u32x2*)w2, dis2, E);
    gatherf8_kernel<<<gGather, B, 0, stream>>>(off, csr, (const u32x2*)w2, (u32x2*)w3, dis2, E);

    // 6. layer 4 + finalize (reads e16 + w1/w2/w3 streams directly)
    finalf8_kernel<<<gGather, B, 0, stream>>>(off, csr,
        (const u32x2*)w1, (const u32x2*)w2, (const u32x2*)w3, (const u32x2*)e16,
        dis, rdis, finU, finIadj, E);
}